// Round 9
// baseline (766.119 us; speedup 1.0000x reference)
//
#include <hip/hip_runtime.h>

#define BB 32
#define MEE 384
#define RRELS 128
#define NNODES 512
#define HSZ 500
#define DHEAD 125
#define NHEADS_ 4
#define HID 2000
#define NLAYER 2

#define KP 512      // padded HSZ
#define HIDP 2048   // padded HID

typedef unsigned short ushort_t;
typedef __attribute__((ext_vector_type(8))) short bf16x8;
typedef __attribute__((ext_vector_type(4))) float f32x4;

static __device__ __forceinline__ unsigned short f2bf(float x) {
    unsigned u = __float_as_uint(x);
    u = u + 0x7fff + ((u >> 16) & 1);   // round-to-nearest-even
    return (unsigned short)(u >> 16);
}

static __device__ __forceinline__ void gload_lds16(const ushort_t* g, ushort_t* l) {
    __builtin_amdgcn_global_load_lds(
        (const __attribute__((address_space(1))) void*)g,
        (__attribute__((address_space(3))) void*)l, 16, 0, 0);
}

// ======================= build nodes (f32 + bf16-padded) =======================
__global__ __launch_bounds__(256) void build_nodes_k(
    const float* __restrict__ ent_vec, const int* __restrict__ entity_num,
    const int* __restrict__ rels, const float* __restrict__ rel_embed,
    float* __restrict__ nodes, ushort_t* __restrict__ xb)
{
    int b = blockIdx.x / NNODES;
    int n = blockIdx.x % NNODES;
    int e = entity_num[b];
    const float* src = nullptr;
    if (n < e)               src = ent_vec + ((size_t)b * MEE + n) * HSZ;
    else if (n < e + RRELS)  src = rel_embed + (size_t)rels[b * RRELS + (n - e)] * HSZ;
    float* dst = nodes + ((size_t)b * NNODES + n) * HSZ;
    ushort_t* xd = xb + ((size_t)b * NNODES + n) * KP;
    for (int d = threadIdx.x; d < KP; d += 256) {
        float v = (src && d < HSZ) ? src[d] : 0.f;
        if (d < HSZ) dst[d] = v;
        xd[d] = (d < HSZ) ? f2bf(v) : 0;
    }
}

// ======================= adjacency -> bitmask =======================
__global__ __launch_bounds__(256) void adj_bits_k(
    const int* __restrict__ adj, unsigned int* __restrict__ bits)
{
    int gw = (blockIdx.x * 256 + threadIdx.x) >> 6;
    int lane = threadIdx.x & 63;
    int v = adj[(size_t)gw * 64 + lane];
    unsigned long long mk = __ballot(v != 0);
    if (lane == 0)  bits[gw * 2]     = (unsigned int)mk;
    if (lane == 32) bits[gw * 2 + 1] = (unsigned int)(mk >> 32);
}

// ======================= all-weights convert (one launch per layer) ============
__global__ __launch_bounds__(256) void wcvt_all_k(
    const float* __restrict__ pWq, const float* __restrict__ pWk,
    const float* __restrict__ pWv, const float* __restrict__ pWo,
    const float* __restrict__ pW1, const float* __restrict__ pW2,
    ushort_t* __restrict__ wqkv, ushort_t* __restrict__ wo,
    ushort_t* __restrict__ w1, ushort_t* __restrict__ w2)
{
    int idx = blockIdx.x * 256 + threadIdx.x;
    if (idx < 786432) {
        int sub = idx / 262144, r = idx % 262144;
        int n = r / 512, k = r % 512;
        const float* W = sub == 0 ? pWq : (sub == 1 ? pWk : pWv);
        wqkv[idx] = (k < 500 && n < 500) ? f2bf(W[k * 500 + n]) : 0;
    } else if (idx < 1048576) {
        int r = idx - 786432; int n = r / 512, k = r % 512;
        wo[r] = (k < 500 && n < 500) ? f2bf(pWo[k * 500 + n]) : 0;
    } else if (idx < 2097152) {
        int r = idx - 1048576; int n = r / 512, k = r % 512;
        w1[r] = (k < 500 && n < 2000) ? f2bf(pW1[k * 2000 + n]) : 0;
    } else if (idx < 3145728) {
        int r = idx - 2097152; int n = r / 2048, k = r % 2048;
        w2[r] = (k < 2000 && n < 500) ? f2bf(pW2[k * 500 + n]) : 0;
    }
}

// ======================= 128x128 bf16 MFMA GEMM (3-deep counted-vmcnt) ==========
// used for O-proj and W2 (narrow-N shapes)
__global__ __launch_bounds__(256, 3) void gemm_mfma_k(
    const ushort_t* __restrict__ A, const ushort_t* __restrict__ Bt,
    const float* __restrict__ bias0,
    float* __restrict__ outF, ushort_t* __restrict__ outB,
    int M, int Np, int Kp, int Nreal,
    const float* __restrict__ prelu)
{
    __shared__ ushort_t Al[3][128 * 32];   // 3 x 8KB
    __shared__ ushort_t Bl[3][128 * 32];   // 3 x 8KB   (48KB total)

    const int nwg = gridDim.x * gridDim.y;
    const int bid = blockIdx.y * gridDim.x + blockIdx.x;
    const int swz = (bid & 7) * (nwg >> 3) + (bid >> 3);
    const int bm = (swz / gridDim.x) * 128;
    const int bn = (swz % gridDim.x) * 128;

    const int tid = threadIdx.x;
    const int wid = tid >> 6, lane = tid & 63;
    const int wr = wid >> 1, wc = wid & 1;
    const int lr = lane & 15, lk = lane >> 4;

    f32x4 acc[4][4];
#pragma unroll
    for (int i = 0; i < 4; ++i)
#pragma unroll
        for (int j = 0; j < 4; ++j)
#pragma unroll
            for (int r = 0; r < 4; ++r) acc[i][j][r] = 0.f;

    const int srow = tid >> 2;
    const int skseg = (tid & 3) * 8;
    const ushort_t* Ag0 = A + (size_t)(bm + srow) * Kp + skseg;
    const ushort_t* Ag1 = A + (size_t)(bm + 64 + srow) * Kp + skseg;
    const ushort_t* Bg0 = Bt + (size_t)(bn + srow) * Kp + skseg;
    const ushort_t* Bg1 = Bt + (size_t)(bn + 64 + srow) * Kp + skseg;

    auto stage = [&](int bi, int k0) {   // 4 vmem instructions per wave
        gload_lds16(Ag0 + k0, &Al[bi][wid * 512]);
        gload_lds16(Ag1 + k0, &Al[bi][2048 + wid * 512]);
        gload_lds16(Bg0 + k0, &Bl[bi][wid * 512]);
        gload_lds16(Bg1 + k0, &Bl[bi][2048 + wid * 512]);
    };

    const int nstep = Kp >> 5;

    stage(0, 0);
    stage(1, 32);
    stage(2, 64);
    asm volatile("s_waitcnt vmcnt(8)" ::: "memory");
    __builtin_amdgcn_s_barrier();
    __builtin_amdgcn_sched_barrier(0);

    int cur = 0;
    for (int t = 0; t < nstep; ++t) {
        bf16x8 af[4], bfr[4];
#pragma unroll
        for (int mi = 0; mi < 4; ++mi)
            af[mi] = *(const bf16x8*)&Al[cur][(wr * 64 + mi * 16 + lr) * 32 + lk * 8];
#pragma unroll
        for (int ni = 0; ni < 4; ++ni)
            bfr[ni] = *(const bf16x8*)&Bl[cur][(wc * 64 + ni * 16 + lr) * 32 + lk * 8];
        __builtin_amdgcn_s_setprio(1);
#pragma unroll
        for (int mi = 0; mi < 4; ++mi)
#pragma unroll
            for (int ni = 0; ni < 4; ++ni)
                acc[mi][ni] = __builtin_amdgcn_mfma_f32_16x16x32_bf16(
                    af[mi], bfr[ni], acc[mi][ni], 0, 0, 0);
        __builtin_amdgcn_s_setprio(0);

        if (t == nstep - 1) break;

        __builtin_amdgcn_sched_barrier(0);
        __builtin_amdgcn_s_barrier();
        __builtin_amdgcn_sched_barrier(0);

        if (t + 3 < nstep) {
            stage(cur, (t + 3) * 32);
            asm volatile("s_waitcnt vmcnt(8)" ::: "memory");
        } else if (t + 3 == nstep) {
            asm volatile("s_waitcnt vmcnt(4)" ::: "memory");
        } else {
            asm volatile("s_waitcnt vmcnt(0)" ::: "memory");
        }
        __builtin_amdgcn_sched_barrier(0);
        __builtin_amdgcn_s_barrier();
        __builtin_amdgcn_sched_barrier(0);

        cur = cur + 1; if (cur == 3) cur = 0;
    }

#pragma unroll
    for (int ni = 0; ni < 4; ++ni) {
        int col = bn + wc * 64 + ni * 16 + lr;
        bool cok = col < Nreal;
        float bv = cok ? bias0[col] : 0.f;
        float pv = (prelu && cok) ? prelu[col] : 0.f;
#pragma unroll
        for (int mi = 0; mi < 4; ++mi) {
            int row0 = bm + wr * 64 + mi * 16 + lk * 4;
#pragma unroll
            for (int r = 0; r < 4; ++r) {
                int row = row0 + r;
                float val = acc[mi][ni][r] + bv;
                if (prelu) val = val > 0.f ? val : pv * val;
                if (outF && cok) outF[(size_t)row * Nreal + col] = val;
                if (outB) outB[(size_t)row * Np + col] = cok ? f2bf(val) : 0;
            }
        }
    }
}

// ======================= 256x256 bf16 MFMA GEMM (8 waves, 3-deep counted-vmcnt) =
// Big-shape kernel: used for fused QKV (mode 1) and W1 (mode 0 + prelu).
// mode 1: Np=1536, col region 0->outB(qh), 1->outK(kh), 2->outV(vh), [bh][512][128]
__global__ __launch_bounds__(512, 2) void gemm256_k(
    const ushort_t* __restrict__ A, const ushort_t* __restrict__ Bt,
    const float* __restrict__ bias0, const float* __restrict__ bias1,
    const float* __restrict__ bias2,
    float* __restrict__ outF, ushort_t* __restrict__ outB,
    ushort_t* __restrict__ outK, ushort_t* __restrict__ outV,
    int M, int Np, int Kp, int Nreal,
    const float* __restrict__ prelu, int mode)
{
    __shared__ ushort_t Al[3][256 * 32];   // 3 x 16KB
    __shared__ ushort_t Bl[3][256 * 32];   // 3 x 16KB  (96KB total)

    const int nwg = gridDim.x * gridDim.y;
    const int bid = blockIdx.y * gridDim.x + blockIdx.x;
    const int swz = (bid & 7) * (nwg >> 3) + (bid >> 3);
    const int bm = (swz / gridDim.x) * 256;
    const int bn = (swz % gridDim.x) * 256;

    const int tid = threadIdx.x;
    const int wid = tid >> 6, lane = tid & 63;   // 8 waves
    const int wr = wid >> 2, wc = wid & 3;        // 2M x 4N wave grid
    const int lr = lane & 15, lk = lane >> 4;

    f32x4 acc[8][4];   // 128 VGPR accumulator (128 rows x 64 cols per wave)
#pragma unroll
    for (int i = 0; i < 8; ++i)
#pragma unroll
        for (int j = 0; j < 4; ++j)
#pragma unroll
            for (int r = 0; r < 4; ++r) acc[i][j][r] = 0.f;

    auto stage = [&](int bi, int k0) {   // 4 vmem instructions per wave
#pragma unroll
        for (int i = 0; i < 2; ++i) {
            int ch = i * 8 + wid;        // 16 chunks of 16 rows
            gload_lds16(A + (size_t)(bm + ch * 16 + (lane >> 2)) * Kp + k0 + (lane & 3) * 8,
                        &Al[bi][ch * 512]);
        }
#pragma unroll
        for (int i = 0; i < 2; ++i) {
            int ch = i * 8 + wid;
            gload_lds16(Bt + (size_t)(bn + ch * 16 + (lane >> 2)) * Kp + k0 + (lane & 3) * 8,
                        &Bl[bi][ch * 512]);
        }
    };

    const int nstep = Kp >> 5;   // 16 (K=512)

    stage(0, 0);
    stage(1, 32);
    stage(2, 64);
    asm volatile("s_waitcnt vmcnt(8)" ::: "memory");
    __builtin_amdgcn_s_barrier();
    __builtin_amdgcn_sched_barrier(0);

    int cur = 0;
    for (int t = 0; t < nstep; ++t) {
        bf16x8 af[8], bfr[4];
#pragma unroll
        for (int mi = 0; mi < 8; ++mi)
            af[mi] = *(const bf16x8*)&Al[cur][(wr * 128 + mi * 16 + lr) * 32 + lk * 8];
#pragma unroll
        for (int ni = 0; ni < 4; ++ni)
            bfr[ni] = *(const bf16x8*)&Bl[cur][(wc * 64 + ni * 16 + lr) * 32 + lk * 8];
        __builtin_amdgcn_s_setprio(1);
#pragma unroll
        for (int mi = 0; mi < 8; ++mi)
#pragma unroll
            for (int ni = 0; ni < 4; ++ni)
                acc[mi][ni] = __builtin_amdgcn_mfma_f32_16x16x32_bf16(
                    af[mi], bfr[ni], acc[mi][ni], 0, 0, 0);
        __builtin_amdgcn_s_setprio(0);

        if (t == nstep - 1) break;

        __builtin_amdgcn_sched_barrier(0);
        __builtin_amdgcn_s_barrier();
        __builtin_amdgcn_sched_barrier(0);

        if (t + 3 < nstep) {
            stage(cur, (t + 3) * 32);
            asm volatile("s_waitcnt vmcnt(8)" ::: "memory");
        } else if (t + 3 == nstep) {
            asm volatile("s_waitcnt vmcnt(4)" ::: "memory");
        } else {
            asm volatile("s_waitcnt vmcnt(0)" ::: "memory");
        }
        __builtin_amdgcn_sched_barrier(0);
        __builtin_amdgcn_s_barrier();
        __builtin_amdgcn_sched_barrier(0);

        cur = cur + 1; if (cur == 3) cur = 0;
    }

    if (mode == 1) {
#pragma unroll
        for (int ni = 0; ni < 4; ++ni) {
            int col = bn + wc * 64 + ni * 16 + lr;
            int reg = col >> 9, c = col & 511;
            bool cok = c < 500;
            int hh, dh;
            if (cok) { hh = c / 125; dh = c - hh * 125; }
            else     { hh = (c - 500) / 3; dh = 125 + (c - 500) % 3; }
            const float* bp = reg == 0 ? bias0 : (reg == 1 ? bias1 : bias2);
            float bv = cok ? bp[c] : 0.f;
            ushort_t* dst = reg == 0 ? outB : (reg == 1 ? outK : outV);
#pragma unroll
            for (int mi = 0; mi < 8; ++mi) {
                int row0 = bm + wr * 128 + mi * 16 + lk * 4;
                int b_ = row0 >> 9, n0 = row0 & 511;
                size_t bh = (size_t)b_ * 4 + hh;
#pragma unroll
                for (int r = 0; r < 4; ++r) {
                    float val = acc[mi][ni][r] + bv;
                    dst[(bh * 512 + n0 + r) * 128 + dh] = cok ? f2bf(val) : 0;
                }
            }
        }
    } else {
#pragma unroll
        for (int ni = 0; ni < 4; ++ni) {
            int col = bn + wc * 64 + ni * 16 + lr;
            bool cok = col < Nreal;
            float bv = cok ? bias0[col] : 0.f;
            float pv = (prelu && cok) ? prelu[col] : 0.f;
#pragma unroll
            for (int mi = 0; mi < 8; ++mi) {
                int row0 = bm + wr * 128 + mi * 16 + lk * 4;
#pragma unroll
                for (int r = 0; r < 4; ++r) {
                    int row = row0 + r;
                    float val = acc[mi][ni][r] + bv;
                    if (prelu) val = val > 0.f ? val : pv * val;
                    if (outF && cok) outF[(size_t)row * Nreal + col] = val;
                    if (outB) outB[(size_t)row * Np + col] = cok ? f2bf(val) : 0;
                }
            }
        }
    }
}

// ======================= V head-layout transpose: vh[bh][512][128] -> vT[bh][128][512]
__global__ __launch_bounds__(256) void vt_k(
    const ushort_t* __restrict__ vh, ushort_t* __restrict__ vT)
{
    int blk = blockIdx.x;
    int dt = blk & 1;          // d-tile (64)
    int nt = (blk >> 1) & 7;   // n-tile (64)
    int bh = blk >> 4;
    int tid = threadIdx.x;
    __shared__ ushort_t T[64 * 64];    // XOR-swizzled by (row&7)

#pragma unroll
    for (int i = 0; i < 2; ++i) {
        int c = tid * 2 + i;           // 0..511 chunks of 8
        int row = c >> 3, c8 = c & 7;
        bf16x8 v = *(const bf16x8*)&vh[((size_t)bh * 512 + nt * 64 + row) * 128 + dt * 64 + c8 * 8];
        *(bf16x8*)&T[row * 64 + ((c8 ^ (row & 7)) << 3)] = v;
    }
    __syncthreads();
#pragma unroll
    for (int i = 0; i < 2; ++i) {
        int c = tid * 2 + i;
        int drow = c >> 3, n8 = (c & 7) * 8;
        bf16x8 o;
#pragma unroll
        for (int j = 0; j < 8; ++j) {
            int n = n8 + j;
            o[j] = (short)T[n * 64 + ((((drow >> 3) ^ (n & 7)) << 3)) + (drow & 7)];
        }
        *(bf16x8*)&vT[((size_t)bh * 128 + dt * 64 + drow) * 512 + nt * 64 + n8] = o;
    }
}

// ======================= MFMA flash attention v2 =======================
#define KTT 64
__global__ __launch_bounds__(256, 2) void attn_mfma_k(
    const ushort_t* __restrict__ qh, const ushort_t* __restrict__ kh,
    const ushort_t* __restrict__ vT, const unsigned int* __restrict__ abits,
    ushort_t* __restrict__ ctxb)
{
    __shared__ ushort_t Kl[2][KTT * 128];    // 2 x 16KB
    __shared__ ushort_t Vl[2][128 * KTT];    // 2 x 16KB
    __shared__ ushort_t Pl[4][32 * KTT];     // 16KB

    const int bid = blockIdx.x;
    const int wg = (bid & 7) * 64 + (bid >> 3);   // 512 wgs: chunked XCD swizzle
    const int qt2 = wg & 3, bh = wg >> 2;
    const int b = bh >> 2, h = bh & 3;
    const int tid = threadIdx.x, wid = tid >> 6, lane = tid & 63;
    const int lr = lane & 15, lk = lane >> 4;
    const int q0 = qt2 * 128 + wid * 32;          // wave's 32 q rows
    const float scale = 0.08944271909999159f;     // 1/sqrt(125)

    bf16x8 qa[2][4];
#pragma unroll
    for (int t = 0; t < 2; ++t) {
        const ushort_t* qbase = qh + ((size_t)bh * 512 + q0 + t * 16 + lr) * 128;
#pragma unroll
        for (int ks = 0; ks < 4; ++ks)
            qa[t][ks] = *(const bf16x8*)&qbase[ks * 32 + lk * 8];
    }

    f32x4 accO[2][8];
#pragma unroll
    for (int t = 0; t < 2; ++t)
#pragma unroll
        for (int i = 0; i < 8; ++i)
#pragma unroll
            for (int r = 0; r < 4; ++r) accO[t][i][r] = 0.f;
    float m_[2][4], l_[2][4];
#pragma unroll
    for (int t = 0; t < 2; ++t)
#pragma unroll
        for (int r = 0; r < 4; ++r) { m_[t][r] = -3e38f; l_[t][r] = 0.f; }

    const unsigned int* ab = abits + ((size_t)b * NNODES + q0) * 16;

    auto stage = [&](int bi, int kt) {
#pragma unroll
        for (int i = 0; i < 4; ++i) {
            int linear = (wid * 4 + i) * 64 + lane;
            int row = linear >> 4, cc = linear & 15;
            int cs = cc ^ (row & 7);
            gload_lds16(kh + ((size_t)bh * 512 + kt * 64 + row) * 128 + cs * 8,
                        &Kl[bi][(wid * 4 + i) * 512]);
        }
#pragma unroll
        for (int i = 0; i < 4; ++i) {
            int linear = (wid * 4 + i) * 64 + lane;
            int row = linear >> 3, cc = linear & 7;
            int cs = cc ^ (row & 7);
            gload_lds16(vT + ((size_t)bh * 128 + row) * 512 + kt * 64 + cs * 8,
                        &Vl[bi][(wid * 4 + i) * 512]);
        }
    };

    stage(0, 0);
    __syncthreads();
    int cur = 0;

    for (int kt = 0; kt < NNODES / KTT; ++kt) {
        if (kt < NNODES / KTT - 1) stage(cur ^ 1, kt + 1);  // prefetch under compute

        unsigned int mw[2][4][2];
#pragma unroll
        for (int t = 0; t < 2; ++t)
#pragma unroll
            for (int r = 0; r < 4; ++r) {
                int qrow = t * 16 + lk * 4 + r;
                mw[t][r][0] = ab[qrow * 16 + kt * 2];
                mw[t][r][1] = ab[qrow * 16 + kt * 2 + 1];
            }

#pragma unroll
        for (int t = 0; t < 2; ++t) {
            f32x4 accS[4];
#pragma unroll
            for (int ni = 0; ni < 4; ++ni)
#pragma unroll
                for (int r = 0; r < 4; ++r) accS[ni][r] = 0.f;
            __builtin_amdgcn_s_setprio(1);
#pragma unroll
            for (int ks = 0; ks < 4; ++ks) {
#pragma unroll
                for (int ni = 0; ni < 4; ++ni) {
                    int row = ni * 16 + lr;
                    int ch = (ks * 4 + lk) ^ (row & 7);
                    bf16x8 kb = *(const bf16x8*)&Kl[cur][row * 128 + ch * 8];
                    accS[ni] = __builtin_amdgcn_mfma_f32_16x16x32_bf16(
                        qa[t][ks], kb, accS[ni], 0, 0, 0);
                }
            }
            __builtin_amdgcn_s_setprio(0);
#pragma unroll
            for (int r = 0; r < 4; ++r) {
                float s[4];
#pragma unroll
                for (int ni = 0; ni < 4; ++ni) {
                    unsigned int word = mw[t][r][ni >> 1];
                    int bit = (ni & 1) * 16 + lr;
                    bool on = (word >> bit) & 1u;
                    s[ni] = on ? accS[ni][r] * scale : -1e9f;
                }
                float rowmax = fmaxf(fmaxf(s[0], s[1]), fmaxf(s[2], s[3]));
                rowmax = fmaxf(rowmax, __shfl_xor(rowmax, 1));
                rowmax = fmaxf(rowmax, __shfl_xor(rowmax, 2));
                rowmax = fmaxf(rowmax, __shfl_xor(rowmax, 4));
                rowmax = fmaxf(rowmax, __shfl_xor(rowmax, 8));
                float mnew = fmaxf(m_[t][r], rowmax);
                float f = __expf(m_[t][r] - mnew);
                m_[t][r] = mnew;
                float p[4], rs = 0.f;
#pragma unroll
                for (int ni = 0; ni < 4; ++ni) { p[ni] = __expf(s[ni] - mnew); rs += p[ni]; }
                rs += __shfl_xor(rs, 1);
                rs += __shfl_xor(rs, 2);
                rs += __shfl_xor(rs, 4);
                rs += __shfl_xor(rs, 8);
                l_[t][r] = l_[t][r] * f + rs;
#pragma unroll
                for (int di = 0; di < 8; ++di) accO[t][di][r] *= f;
                int q = t * 16 + lk * 4 + r;
#pragma unroll
                for (int ni = 0; ni < 4; ++ni) {
                    int key = ni * 16 + lr;
                    Pl[wid][q * 64 + (((key >> 3) ^ (q & 7)) << 3) + (key & 7)] = f2bf(p[ni]);
                }
            }
        }

#pragma unroll
        for (int t = 0; t < 2; ++t) {
#pragma unroll
            for (int ksp = 0; ksp < 2; ++ksp) {
                int q = t * 16 + lr;
                int k0p = ksp * 32 + lk * 8;
                bf16x8 pa = *(const bf16x8*)&Pl[wid][q * 64 + (((k0p >> 3) ^ (q & 7)) << 3)];
                __builtin_amdgcn_s_setprio(1);
#pragma unroll
                for (int di = 0; di < 8; ++di) {
                    int row = di * 16 + lr;
                    int ch = (ksp * 4 + lk) ^ (row & 7);
                    bf16x8 vb = *(const bf16x8*)&Vl[cur][row * 64 + ch * 8];
                    accO[t][di] = __builtin_amdgcn_mfma_f32_16x16x32_bf16(
                        pa, vb, accO[t][di], 0, 0, 0);
                }
                __builtin_amdgcn_s_setprio(0);
            }
        }
        __syncthreads();
        cur ^= 1;
    }

    float inv[2][4];
#pragma unroll
    for (int t = 0; t < 2; ++t)
#pragma unroll
        for (int r = 0; r < 4; ++r) inv[t][r] = 1.f / l_[t][r];
#pragma unroll
    for (int t = 0; t < 2; ++t)
#pragma unroll
        for (int di = 0; di < 8; ++di) {
            int d = di * 16 + lr;
            if (d < DHEAD) {
#pragma unroll
                for (int r = 0; r < 4; ++r) {
                    int qg = q0 + t * 16 + lk * 4 + r;
                    ctxb[((size_t)b * NNODES + qg) * KP + h * DHEAD + d] =
                        f2bf(accO[t][di][r] * inv[t][r]);
                }
            }
        }
    if (h == 3) {
        int row = q0 + (lane & 31);
        int c0 = 500 + (lane >> 5) * 6;
#pragma unroll
        for (int j = 0; j < 6; ++j)
            ctxb[((size_t)b * NNODES + row) * KP + c0 + j] = 0;
    }
}

// ======================= layernorm (residual opt) -> f32 + bf16-padded =========
__global__ __launch_bounds__(256) void ln_k(
    const float* __restrict__ x, const float* __restrict__ res,
    const float* __restrict__ g, const float* __restrict__ bta,
    float* __restrict__ outF, ushort_t* __restrict__ outB)
{
    size_t row = blockIdx.x;
    const float* xr = x + row * HSZ;
    const float* rr = res ? res + row * HSZ : nullptr;
    int t = threadIdx.x;
    float v[2];
    float s = 0.f, s2 = 0.f;
#pragma unroll
    for (int i = 0; i < 2; ++i) {
        int d = t + i * 256;
        float val = 0.f;
        if (d < HSZ) { val = xr[d]; if (rr) val += rr[d]; }
        v[i] = val; s += val; s2 += val * val;
    }
    __shared__ float red[8];
    int wave = t >> 6, lane = t & 63;
    for (int o = 1; o < 64; o <<= 1) { s += __shfl_xor(s, o); s2 += __shfl_xor(s2, o); }
    if (lane == 0) { red[wave] = s; red[4 + wave] = s2; }
    __syncthreads();
    s  = red[0] + red[1] + red[2] + red[3];
    s2 = red[4] + red[5] + red[6] + red[7];
    float mean = s / HSZ;
    float var  = s2 / HSZ - mean * mean;
    float rstd = rsqrtf(var + 1e-5f);
    float* orow = outF + row * HSZ;
    ushort_t* brow = outB + row * KP;
#pragma unroll
    for (int i = 0; i < 2; ++i) {
        int d = t + i * 256;
        if (d < HSZ) {
            float o = (v[i] - mean) * rstd * g[d] + bta[d];
            orow[d] = o;
            brow[d] = f2bf(o);
        } else if (d < KP) {
            brow[d] = 0;
        }
    }
}

// ======================= finalize: glob, node_emb, mask =======================
__global__ __launch_bounds__(256) void finalize_k(
    const float* __restrict__ nodes, const int* __restrict__ entity_num,
    float* __restrict__ out)
{
    int b = blockIdx.x / NNODES;
    int n = blockIdx.x % NNODES;
    int e = entity_num[b];
    int size = e + RRELS;
    const float* src = nodes + ((size_t)b * NNODES + n) * HSZ;
    float* ne = out + (size_t)BB * HSZ + ((size_t)b * NNODES + n) * HSZ;
    bool valid = n < size;
    for (int d = threadIdx.x; d < HSZ; d += 256) ne[d] = valid ? src[d] : 0.f;
    if (n == e) {
        float* gl = out + (size_t)b * HSZ;
        for (int d = threadIdx.x; d < HSZ; d += 256) gl[d] = src[d];
    }
    if (threadIdx.x == 0) {
        out[(size_t)BB * HSZ + (size_t)BB * NNODES * HSZ + (size_t)b * NNODES + n] =
            (n <= size) ? 1.f : 0.f;
    }
}

// ======================= host =======================
extern "C" void kernel_launch(void* const* d_in, const int* in_sizes, int n_in,
                              void* d_out, int out_size, void* d_ws, size_t ws_size,
                              hipStream_t stream)
{
    const float* ent_vec    = (const float*)d_in[0];
    const int*   entity_num = (const int*)d_in[1];
    const int*   rels       = (const int*)d_in[2];
    const int*   adj        = (const int*)d_in[3];
    const float* rel_embed  = (const float*)d_in[4];
    const float* Wq = (const float*)d_in[5],  *bq = (const float*)d_in[6];
    const float* Wk = (const float*)d_in[7],  *bk = (const float*)d_in[8];
    const float* Wv = (const float*)d_in[9],  *bv = (const float*)d_in[10];
    const float* Wo = (const float*)d_in[11], *bo = (const float*)d_in[12];
    const float* W1 = (const float*)d_in[13], *b1 = (const float*)d_in[14];
    const float* W2 = (const float*)d_in[15], *b2 = (const float*)d_in[16];
    const float* ln1g = (const float*)d_in[17], *ln1b = (const float*)d_in[18];
    const float* ln2g = (const float*)d_in[19], *ln2b = (const float*)d_in[20];
    const float* pa = (const float*)d_in[21];

    const int M = BB * NNODES;               // 16384
    const size_t S = (size_t)M * HSZ;        // 8,192,000 floats
    float* Af = (float*)d_ws;                // nodesF
    float* Bf = Af + S;                      // o f32 / vh+vT scratch during attn
    float* Cf = Bf + S;                      // t f32 (tail of vT spills here)
    float* Df = Cf + S;                      // f f32
    ushort_t* b16 = (ushort_t*)(Df + S);
    const size_t SP = (size_t)M * KP;        // 8,388,608
    ushort_t* Xb   = b16;
    ushort_t* ctxb = Xb + SP;
    ushort_t* tb   = ctxb + SP;
    ushort_t* h1b  = tb + SP;                // 8192*2048 bf16 = qh+kh scratch
    ushort_t* wqkvb = h1b + (size_t)8192 * HIDP;  // 3*512*512
    ushort_t* wob  = wqkvb + 3 * KP * KP;
    ushort_t* w1b  = wob + KP * KP;          // [HIDP][KP]
    ushort_t* w2b  = w1b + (size_t)HIDP * KP;// [KP][HIDP]

    const size_t HBUF = (size_t)BB * NHEADS_ * NNODES * 128;  // 8,388,608
    ushort_t* qh = h1b;                       // dead outside attn phase
    ushort_t* kh = h1b + HBUF;
    ushort_t* vh = (ushort_t*)Bf;             // Bf dead during attn phase
    ushort_t* vTb = vh + HBUF;                // spills 0.78MB into Cf head (dead then)

    unsigned int* abits = (unsigned int*)d_out;  // overwritten by finalize_k

    build_nodes_k<<<BB * NNODES, 256, 0, stream>>>(ent_vec, entity_num, rels, rel_embed, Af, Xb);
    adj_bits_k<<<(BB * NNODES * NNODES) / 64 / 4, 256, 0, stream>>>(adj, abits);

    for (int l = 0; l < NLAYER; ++l) {
        const float* bq_l = bq + (size_t)l * HSZ;
        const float* bk_l = bk + (size_t)l * HSZ;
        const float* bv_l = bv + (size_t)l * HSZ;
        const float* bo_l = bo + (size_t)l * HSZ;
        const float* b1_l = b1 + (size_t)l * HID;
        const float* b2_l = b2 + (size_t)l * HSZ;
        const float* pa_l = pa + (size_t)l * HID;

        wcvt_all_k<<<12288, 256, 0, stream>>>(
            Wq + (size_t)l * HSZ * HSZ, Wk + (size_t)l * HSZ * HSZ,
            Wv + (size_t)l * HSZ * HSZ, Wo + (size_t)l * HSZ * HSZ,
            W1 + (size_t)l * HSZ * HID, W2 + (size_t)l * HID * HSZ,
            wqkvb, wob, w1b, w2b);

        // fused QKV on 256x256 kernel: writes qh, kh, vh (head row-layout)
        dim3 gQKV(1536 / 256, M / 256);  // (6, 64) = 384 wgs
        gemm256_k<<<gQKV, 512, 0, stream>>>(Xb, wqkvb, bq_l, bk_l, bv_l,
                                            nullptr, qh, kh, vh,
                                            M, 1536, KP, HSZ, nullptr, 1);

        vt_k<<<BB * NHEADS_ * 16, 256, 0, stream>>>(vh, vTb);
        attn_mfma_k<<<BB * NHEADS_ * 4, 256, 0, stream>>>(qh, kh, vTb, abits, ctxb);

        dim3 gO(KP / 128, M / 128);      // (4, 128)
        gemm_mfma_k<<<gO, 256, 0, stream>>>(ctxb, wob, bo_l,
                                            Bf, nullptr,
                                            M, KP, KP, HSZ, nullptr);
        ln_k<<<M, 256, 0, stream>>>(Bf, nullptr, ln1g + (size_t)l * HSZ, ln1b + (size_t)l * HSZ, Cf, tb);

        for (int c = 0; c < 2; ++c) {
            const ushort_t* tch = tb + (size_t)c * 8192 * KP;
            float* fch = Df + (size_t)c * 8192 * HSZ;
            dim3 g1(HIDP / 256, 8192 / 256);   // (8, 32) = 256 wgs
            gemm256_k<<<g1, 512, 0, stream>>>(tch, w1b, b1_l, nullptr, nullptr,
                                              nullptr, h1b, nullptr, nullptr,
                                              8192, HIDP, KP, HID, pa_l, 0);
            dim3 g2(KP / 128, 8192 / 128);     // (4, 64)
            gemm_mfma_k<<<g2, 256, 0, stream>>>(h1b, w2b, b2_l,
                                                fch, nullptr,
                                                8192, KP, HIDP, HSZ, nullptr);
        }
        ln_k<<<M, 256, 0, stream>>>(Df, Cf, ln2g + (size_t)l * HSZ, ln2b + (size_t)l * HSZ, Af, Xb);
    }

    finalize_k<<<BB * NNODES, 256, 0, stream>>>(Af, entity_num, (float*)d_out);
}

// Round 10
// 566.471 us; speedup vs baseline: 1.3524x; 1.3524x over previous
//
#include <hip/hip_runtime.h>

#define BB 32
#define MEE 384
#define RRELS 128
#define NNODES 512
#define HSZ 500
#define DHEAD 125
#define NHEADS_ 4
#define HID 2000
#define NLAYER 2

#define KP 512      // padded HSZ
#define HIDP 2048   // padded HID

typedef unsigned short ushort_t;
typedef __attribute__((ext_vector_type(8))) short bf16x8;
typedef __attribute__((ext_vector_type(4))) float f32x4;
typedef __attribute__((ext_vector_type(4))) short s16x4;

static __device__ __forceinline__ unsigned short f2bf(float x) {
    unsigned u = __float_as_uint(x);
    u = u + 0x7fff + ((u >> 16) & 1);   // round-to-nearest-even
    return (unsigned short)(u >> 16);
}
static __device__ __forceinline__ float bf2f(unsigned short b) {
    return __uint_as_float((unsigned)b << 16);
}

static __device__ __forceinline__ void gload_lds16(const ushort_t* g, ushort_t* l) {
    __builtin_amdgcn_global_load_lds(
        (const __attribute__((address_space(1))) void*)g,
        (__attribute__((address_space(3))) void*)l, 16, 0, 0);
}

// ======================= build nodes (bf16-padded) =======================
__global__ __launch_bounds__(256) void build_nodes_k(
    const float* __restrict__ ent_vec, const int* __restrict__ entity_num,
    const int* __restrict__ rels, const float* __restrict__ rel_embed,
    ushort_t* __restrict__ xb)
{
    int b = blockIdx.x / NNODES;
    int n = blockIdx.x % NNODES;
    int e = entity_num[b];
    const float* src = nullptr;
    if (n < e)               src = ent_vec + ((size_t)b * MEE + n) * HSZ;
    else if (n < e + RRELS)  src = rel_embed + (size_t)rels[b * RRELS + (n - e)] * HSZ;
    ushort_t* xd = xb + ((size_t)b * NNODES + n) * KP;
    for (int d = threadIdx.x; d < KP; d += 256)
        xd[d] = (src && d < HSZ) ? f2bf(src[d]) : 0;
}

// ======================= adjacency -> bitmask =======================
__global__ __launch_bounds__(256) void adj_bits_k(
    const int* __restrict__ adj, unsigned int* __restrict__ bits)
{
    int gw = (blockIdx.x * 256 + threadIdx.x) >> 6;
    int lane = threadIdx.x & 63;
    int v = adj[(size_t)gw * 64 + lane];
    unsigned long long mk = __ballot(v != 0);
    if (lane == 0)  bits[gw * 2]     = (unsigned int)mk;
    if (lane == 32) bits[gw * 2 + 1] = (unsigned int)(mk >> 32);
}

// ======================= all-weights convert (one launch per layer) ============
__global__ __launch_bounds__(256) void wcvt_all_k(
    const float* __restrict__ pWq, const float* __restrict__ pWk,
    const float* __restrict__ pWv, const float* __restrict__ pWo,
    const float* __restrict__ pW1, const float* __restrict__ pW2,
    ushort_t* __restrict__ wqkv, ushort_t* __restrict__ wo,
    ushort_t* __restrict__ w1, ushort_t* __restrict__ w2)
{
    int idx = blockIdx.x * 256 + threadIdx.x;
    if (idx < 786432) {
        int sub = idx / 262144, r = idx % 262144;
        int n = r / 512, k = r % 512;
        const float* W = sub == 0 ? pWq : (sub == 1 ? pWk : pWv);
        wqkv[idx] = (k < 500 && n < 500) ? f2bf(W[k * 500 + n]) : 0;
    } else if (idx < 1048576) {
        int r = idx - 786432; int n = r / 512, k = r % 512;
        wo[r] = (k < 500 && n < 500) ? f2bf(pWo[k * 500 + n]) : 0;
    } else if (idx < 2097152) {
        int r = idx - 1048576; int n = r / 512, k = r % 512;
        w1[r] = (k < 500 && n < 2000) ? f2bf(pW1[k * 2000 + n]) : 0;
    } else if (idx < 3145728) {
        int r = idx - 2097152; int n = r / 2048, k = r % 2048;
        w2[r] = (k < 2000 && n < 500) ? f2bf(pW2[k * 500 + n]) : 0;
    }
}

// ======================= bf16 MFMA GEMM (128x128, BK=32, 2-phase dbuf) ==========
// Proven-best R5 structure. A: [M, Kp] bf16. Bt: [Np, Kp] bf16 (W^T).
// mode 0: outB = bf16 [M, Np], zero-padded cols, optional PReLU
// mode 1: fused QKV, Np=1536: region 0->outB(qh), 1->outK(kh),
//         2->outV = V^T [bh][128][512] (scatter, s16x4)
__global__ __launch_bounds__(256, 2) void gemm_mfma_k(
    const ushort_t* __restrict__ A, const ushort_t* __restrict__ Bt,
    const float* __restrict__ bias0, const float* __restrict__ bias1,
    const float* __restrict__ bias2,
    ushort_t* __restrict__ outB, ushort_t* __restrict__ outK,
    ushort_t* __restrict__ outV,
    int M, int Np, int Kp, int Nreal,
    const float* __restrict__ prelu, int mode)
{
    __shared__ ushort_t Al[2][128 * 32];
    __shared__ ushort_t Bl[2][128 * 32];

    // bijective XCD-chunked swizzle (all grids have nwg % 8 == 0)
    const int nwg = gridDim.x * gridDim.y;
    const int bid = blockIdx.y * gridDim.x + blockIdx.x;
    const int swz = (bid & 7) * (nwg >> 3) + (bid >> 3);
    const int bm = (swz / gridDim.x) * 128;
    const int bn = (swz % gridDim.x) * 128;

    const int tid = threadIdx.x;
    const int wid = tid >> 6, lane = tid & 63;
    const int wr = wid >> 1, wc = wid & 1;
    const int lr = lane & 15, lk = lane >> 4;

    f32x4 acc[4][4];
#pragma unroll
    for (int i = 0; i < 4; ++i)
#pragma unroll
        for (int j = 0; j < 4; ++j)
#pragma unroll
            for (int r = 0; r < 4; ++r) acc[i][j][r] = 0.f;

    const int srow = tid >> 2;
    const int skseg = (tid & 3) * 8;
    const ushort_t* Ag0 = A + (size_t)(bm + srow) * Kp + skseg;
    const ushort_t* Ag1 = A + (size_t)(bm + 64 + srow) * Kp + skseg;
    const ushort_t* Bg0 = Bt + (size_t)(bn + srow) * Kp + skseg;
    const ushort_t* Bg1 = Bt + (size_t)(bn + 64 + srow) * Kp + skseg;

    auto stage = [&](int bi, int k0) {
        gload_lds16(Ag0 + k0, &Al[bi][wid * 512]);
        gload_lds16(Ag1 + k0, &Al[bi][2048 + wid * 512]);
        gload_lds16(Bg0 + k0, &Bl[bi][wid * 512]);
        gload_lds16(Bg1 + k0, &Bl[bi][2048 + wid * 512]);
    };

    stage(0, 0);
    __syncthreads();
    int cur = 0;

    for (int k0 = 0; k0 < Kp; k0 += 32) {
        if (k0 + 32 < Kp) stage(cur ^ 1, k0 + 32);   // prefetch under compute

        bf16x8 af[4], bfr[4];
#pragma unroll
        for (int mi = 0; mi < 4; ++mi)
            af[mi] = *(const bf16x8*)&Al[cur][(wr * 64 + mi * 16 + lr) * 32 + lk * 8];
#pragma unroll
        for (int ni = 0; ni < 4; ++ni)
            bfr[ni] = *(const bf16x8*)&Bl[cur][(wc * 64 + ni * 16 + lr) * 32 + lk * 8];
        __builtin_amdgcn_s_setprio(1);
#pragma unroll
        for (int mi = 0; mi < 4; ++mi)
#pragma unroll
            for (int ni = 0; ni < 4; ++ni)
                acc[mi][ni] = __builtin_amdgcn_mfma_f32_16x16x32_bf16(
                    af[mi], bfr[ni], acc[mi][ni], 0, 0, 0);
        __builtin_amdgcn_s_setprio(0);

        __syncthreads();   // drains prefetch + releases cur buffer
        cur ^= 1;
    }

    if (mode == 1) {
#pragma unroll
        for (int ni = 0; ni < 4; ++ni) {
            int col = bn + wc * 64 + ni * 16 + lr;
            int reg = col >> 9, c = col & 511;
            bool cok = c < 500;
            int hh, dh;
            if (cok) { hh = c / 125; dh = c - hh * 125; }
            else     { hh = (c - 500) / 3; dh = 125 + (c - 500) % 3; }
            const float* bp = reg == 0 ? bias0 : (reg == 1 ? bias1 : bias2);
            float bv = cok ? bp[c] : 0.f;
#pragma unroll
            for (int mi = 0; mi < 4; ++mi) {
                int row0 = bm + wr * 64 + mi * 16 + lk * 4;
                int b_ = row0 >> 9, n0 = row0 & 511;
                size_t bh = (size_t)b_ * 4 + hh;
                if (reg == 2) {
                    s16x4 pk;
#pragma unroll
                    for (int r = 0; r < 4; ++r) {
                        float val = acc[mi][ni][r] + bv;
                        pk[r] = cok ? (short)f2bf(val) : (short)0;
                    }
                    *(s16x4*)&outV[(bh * 128 + dh) * 512 + n0] = pk;
                } else {
                    ushort_t* dst = reg == 0 ? outB : outK;
#pragma unroll
                    for (int r = 0; r < 4; ++r) {
                        float val = acc[mi][ni][r] + bv;
                        dst[(bh * 512 + n0 + r) * 128 + dh] = cok ? f2bf(val) : 0;
                    }
                }
            }
        }
    } else {
#pragma unroll
        for (int ni = 0; ni < 4; ++ni) {
            int col = bn + wc * 64 + ni * 16 + lr;
            bool cok = col < Nreal;
            float bv = cok ? bias0[col] : 0.f;
            float pv = (prelu && cok) ? prelu[col] : 0.f;
#pragma unroll
            for (int mi = 0; mi < 4; ++mi) {
                int row0 = bm + wr * 64 + mi * 16 + lk * 4;
#pragma unroll
                for (int r = 0; r < 4; ++r) {
                    int row = row0 + r;
                    float val = acc[mi][ni][r] + bv;
                    if (prelu) val = val > 0.f ? val : pv * val;
                    outB[(size_t)row * Np + col] = cok ? f2bf(val) : 0;
                }
            }
        }
    }
}

// ======================= MFMA flash attention v2 (unchanged) ====================
#define KTT 64
__global__ __launch_bounds__(256, 2) void attn_mfma_k(
    const ushort_t* __restrict__ qh, const ushort_t* __restrict__ kh,
    const ushort_t* __restrict__ vT, const unsigned int* __restrict__ abits,
    ushort_t* __restrict__ ctxb)
{
    __shared__ ushort_t Kl[2][KTT * 128];    // 2 x 16KB
    __shared__ ushort_t Vl[2][128 * KTT];    // 2 x 16KB
    __shared__ ushort_t Pl[4][32 * KTT];     // 16KB

    const int bid = blockIdx.x;
    const int wg = (bid & 7) * 64 + (bid >> 3);   // 512 wgs: chunked XCD swizzle
    const int qt2 = wg & 3, bh = wg >> 2;
    const int b = bh >> 2, h = bh & 3;
    const int tid = threadIdx.x, wid = tid >> 6, lane = tid & 63;
    const int lr = lane & 15, lk = lane >> 4;
    const int q0 = qt2 * 128 + wid * 32;          // wave's 32 q rows
    const float scale = 0.08944271909999159f;     // 1/sqrt(125)

    bf16x8 qa[2][4];
#pragma unroll
    for (int t = 0; t < 2; ++t) {
        const ushort_t* qbase = qh + ((size_t)bh * 512 + q0 + t * 16 + lr) * 128;
#pragma unroll
        for (int ks = 0; ks < 4; ++ks)
            qa[t][ks] = *(const bf16x8*)&qbase[ks * 32 + lk * 8];
    }

    f32x4 accO[2][8];
#pragma unroll
    for (int t = 0; t < 2; ++t)
#pragma unroll
        for (int i = 0; i < 8; ++i)
#pragma unroll
            for (int r = 0; r < 4; ++r) accO[t][i][r] = 0.f;
    float m_[2][4], l_[2][4];
#pragma unroll
    for (int t = 0; t < 2; ++t)
#pragma unroll
        for (int r = 0; r < 4; ++r) { m_[t][r] = -3e38f; l_[t][r] = 0.f; }

    const unsigned int* ab = abits + ((size_t)b * NNODES + q0) * 16;

    auto stage = [&](int bi, int kt) {
#pragma unroll
        for (int i = 0; i < 4; ++i) {
            int linear = (wid * 4 + i) * 64 + lane;
            int row = linear >> 4, cc = linear & 15;
            int cs = cc ^ (row & 7);
            gload_lds16(kh + ((size_t)bh * 512 + kt * 64 + row) * 128 + cs * 8,
                        &Kl[bi][(wid * 4 + i) * 512]);
        }
#pragma unroll
        for (int i = 0; i < 4; ++i) {
            int linear = (wid * 4 + i) * 64 + lane;
            int row = linear >> 3, cc = linear & 7;
            int cs = cc ^ (row & 7);
            gload_lds16(vT + ((size_t)bh * 128 + row) * 512 + kt * 64 + cs * 8,
                        &Vl[bi][(wid * 4 + i) * 512]);
        }
    };

    stage(0, 0);
    __syncthreads();
    int cur = 0;

    for (int kt = 0; kt < NNODES / KTT; ++kt) {
        if (kt < NNODES / KTT - 1) stage(cur ^ 1, kt + 1);  // prefetch under compute

        unsigned int mw[2][4][2];
#pragma unroll
        for (int t = 0; t < 2; ++t)
#pragma unroll
            for (int r = 0; r < 4; ++r) {
                int qrow = t * 16 + lk * 4 + r;
                mw[t][r][0] = ab[qrow * 16 + kt * 2];
                mw[t][r][1] = ab[qrow * 16 + kt * 2 + 1];
            }

#pragma unroll
        for (int t = 0; t < 2; ++t) {
            f32x4 accS[4];
#pragma unroll
            for (int ni = 0; ni < 4; ++ni)
#pragma unroll
                for (int r = 0; r < 4; ++r) accS[ni][r] = 0.f;
            __builtin_amdgcn_s_setprio(1);
#pragma unroll
            for (int ks = 0; ks < 4; ++ks) {
#pragma unroll
                for (int ni = 0; ni < 4; ++ni) {
                    int row = ni * 16 + lr;
                    int ch = (ks * 4 + lk) ^ (row & 7);
                    bf16x8 kb = *(const bf16x8*)&Kl[cur][row * 128 + ch * 8];
                    accS[ni] = __builtin_amdgcn_mfma_f32_16x16x32_bf16(
                        qa[t][ks], kb, accS[ni], 0, 0, 0);
                }
            }
            __builtin_amdgcn_s_setprio(0);
#pragma unroll
            for (int r = 0; r < 4; ++r) {
                float s[4];
#pragma unroll
                for (int ni = 0; ni < 4; ++ni) {
                    unsigned int word = mw[t][r][ni >> 1];
                    int bit = (ni & 1) * 16 + lr;
                    bool on = (word >> bit) & 1u;
                    s[ni] = on ? accS[ni][r] * scale : -1e9f;
                }
                float rowmax = fmaxf(fmaxf(s[0], s[1]), fmaxf(s[2], s[3]));
                rowmax = fmaxf(rowmax, __shfl_xor(rowmax, 1));
                rowmax = fmaxf(rowmax, __shfl_xor(rowmax, 2));
                rowmax = fmaxf(rowmax, __shfl_xor(rowmax, 4));
                rowmax = fmaxf(rowmax, __shfl_xor(rowmax, 8));
                float mnew = fmaxf(m_[t][r], rowmax);
                float f = __expf(m_[t][r] - mnew);
                m_[t][r] = mnew;
                float p[4], rs = 0.f;
#pragma unroll
                for (int ni = 0; ni < 4; ++ni) { p[ni] = __expf(s[ni] - mnew); rs += p[ni]; }
                rs += __shfl_xor(rs, 1);
                rs += __shfl_xor(rs, 2);
                rs += __shfl_xor(rs, 4);
                rs += __shfl_xor(rs, 8);
                l_[t][r] = l_[t][r] * f + rs;
#pragma unroll
                for (int di = 0; di < 8; ++di) accO[t][di][r] *= f;
                int q = t * 16 + lk * 4 + r;
#pragma unroll
                for (int ni = 0; ni < 4; ++ni) {
                    int key = ni * 16 + lr;
                    Pl[wid][q * 64 + (((key >> 3) ^ (q & 7)) << 3) + (key & 7)] = f2bf(p[ni]);
                }
            }
        }

#pragma unroll
        for (int t = 0; t < 2; ++t) {
#pragma unroll
            for (int ksp = 0; ksp < 2; ++ksp) {
                int q = t * 16 + lr;
                int k0p = ksp * 32 + lk * 8;
                bf16x8 pa = *(const bf16x8*)&Pl[wid][q * 64 + (((k0p >> 3) ^ (q & 7)) << 3)];
                __builtin_amdgcn_s_setprio(1);
#pragma unroll
                for (int di = 0; di < 8; ++di) {
                    int row = di * 16 + lr;
                    int ch = (ksp * 4 + lk) ^ (row & 7);
                    bf16x8 vb = *(const bf16x8*)&Vl[cur][row * 64 + ch * 8];
                    accO[t][di] = __builtin_amdgcn_mfma_f32_16x16x32_bf16(
                        pa, vb, accO[t][di], 0, 0, 0);
                }
                __builtin_amdgcn_s_setprio(0);
            }
        }
        __syncthreads();
        cur ^= 1;
    }

    float inv[2][4];
#pragma unroll
    for (int t = 0; t < 2; ++t)
#pragma unroll
        for (int r = 0; r < 4; ++r) inv[t][r] = 1.f / l_[t][r];
#pragma unroll
    for (int t = 0; t < 2; ++t)
#pragma unroll
        for (int di = 0; di < 8; ++di) {
            int d = di * 16 + lr;
            if (d < DHEAD) {
#pragma unroll
                for (int r = 0; r < 4; ++r) {
                    int qg = q0 + t * 16 + lk * 4 + r;
                    ctxb[((size_t)b * NNODES + qg) * KP + h * DHEAD + d] =
                        f2bf(accO[t][di][r] * inv[t][r]);
                }
            }
        }
    if (h == 3) {
        int row = q0 + (lane & 31);
        int c0 = 500 + (lane >> 5) * 6;
#pragma unroll
        for (int j = 0; j < 6; ++j)
            ctxb[((size_t)b * NNODES + row) * KP + c0 + j] = 0;
    }
}

// ======================= layernorm bf16->bf16 (optional residual, f32 copy) ====
__global__ __launch_bounds__(256) void ln_k(
    const ushort_t* __restrict__ x, const ushort_t* __restrict__ res,
    const float* __restrict__ g, const float* __restrict__ bta,
    ushort_t* __restrict__ outB, float* __restrict__ outF)
{
    size_t row = blockIdx.x;
    const unsigned int* xr = (const unsigned int*)(x + row * KP);
    const unsigned int* rr = res ? (const unsigned int*)(res + row * KP) : nullptr;
    int t = threadIdx.x;           // thread t handles dims 2t, 2t+1
    int d0 = 2 * t;
    unsigned int xv = xr[t];
    float v0 = bf2f((unsigned short)(xv & 0xffff));
    float v1 = bf2f((unsigned short)(xv >> 16));
    if (rr) {
        unsigned int rv = rr[t];
        v0 += bf2f((unsigned short)(rv & 0xffff));
        v1 += bf2f((unsigned short)(rv >> 16));
    }
    if (d0 >= HSZ) v0 = 0.f;
    if (d0 + 1 >= HSZ) v1 = 0.f;
    float s = v0 + v1, s2 = v0 * v0 + v1 * v1;

    __shared__ float red[8];
    int wave = t >> 6, lane = t & 63;
    for (int o = 1; o < 64; o <<= 1) { s += __shfl_xor(s, o); s2 += __shfl_xor(s2, o); }
    if (lane == 0) { red[wave] = s; red[4 + wave] = s2; }
    __syncthreads();
    s  = red[0] + red[1] + red[2] + red[3];
    s2 = red[4] + red[5] + red[6] + red[7];
    float mean = s / HSZ;
    float var  = s2 / HSZ - mean * mean;
    float rstd = rsqrtf(var + 1e-5f);

    float o0 = 0.f, o1 = 0.f;
    if (d0 < HSZ)     o0 = (v0 - mean) * rstd * g[d0] + bta[d0];
    if (d0 + 1 < HSZ) o1 = (v1 - mean) * rstd * g[d0 + 1] + bta[d0 + 1];
    unsigned int pk = (unsigned int)f2bf(o0) | ((unsigned int)f2bf(o1) << 16);
    if (d0 >= HSZ) pk = 0;
    else if (d0 + 1 >= HSZ) pk = (unsigned int)f2bf(o0);
    ((unsigned int*)(outB + row * KP))[t] = pk;
    if (outF) {
        if (d0 < HSZ)     outF[row * HSZ + d0] = o0;
        if (d0 + 1 < HSZ) outF[row * HSZ + d0 + 1] = o1;
    }
}

// ======================= finalize: glob, node_emb, mask =======================
__global__ __launch_bounds__(256) void finalize_k(
    const float* __restrict__ nodes, const int* __restrict__ entity_num,
    float* __restrict__ out)
{
    int b = blockIdx.x / NNODES;
    int n = blockIdx.x % NNODES;
    int e = entity_num[b];
    int size = e + RRELS;
    const float* src = nodes + ((size_t)b * NNODES + n) * HSZ;
    float* ne = out + (size_t)BB * HSZ + ((size_t)b * NNODES + n) * HSZ;
    bool valid = n < size;
    for (int d = threadIdx.x; d < HSZ; d += 256) ne[d] = valid ? src[d] : 0.f;
    if (n == e) {
        float* gl = out + (size_t)b * HSZ;
        for (int d = threadIdx.x; d < HSZ; d += 256) gl[d] = src[d];
    }
    if (threadIdx.x == 0) {
        out[(size_t)BB * HSZ + (size_t)BB * NNODES * HSZ + (size_t)b * NNODES + n] =
            (n <= size) ? 1.f : 0.f;
    }
}

// ======================= host =======================
extern "C" void kernel_launch(void* const* d_in, const int* in_sizes, int n_in,
                              void* d_out, int out_size, void* d_ws, size_t ws_size,
                              hipStream_t stream)
{
    const float* ent_vec    = (const float*)d_in[0];
    const int*   entity_num = (const int*)d_in[1];
    const int*   rels       = (const int*)d_in[2];
    const int*   adj        = (const int*)d_in[3];
    const float* rel_embed  = (const float*)d_in[4];
    const float* Wq = (const float*)d_in[5],  *bq = (const float*)d_in[6];
    const float* Wk = (const float*)d_in[7],  *bk = (const float*)d_in[8];
    const float* Wv = (const float*)d_in[9],  *bv = (const float*)d_in[10];
    const float* Wo = (const float*)d_in[11], *bo = (const float*)d_in[12];
    const float* W1 = (const float*)d_in[13], *b1 = (const float*)d_in[14];
    const float* W2 = (const float*)d_in[15], *b2 = (const float*)d_in[16];
    const float* ln1g = (const float*)d_in[17], *ln1b = (const float*)d_in[18];
    const float* ln2g = (const float*)d_in[19], *ln2b = (const float*)d_in[20];
    const float* pa = (const float*)d_in[21];

    const int M = BB * NNODES;               // 16384
    const size_t SP = (size_t)M * KP;        // 8,388,608 bf16

    ushort_t* Xb   = (ushort_t*)d_ws;        // [M][KP]  nodes bf16
    ushort_t* ctxb = Xb + SP;                // attention context
    ushort_t* tb   = ctxb + SP;              // t (ln1 out)
    ushort_t* ob   = tb + SP;                // o (O-proj out)
    ushort_t* fb   = ob + SP;                // f (W2 out)
    ushort_t* h1b  = fb + SP;                // [16384][2048] h1 (67.1MB)
    ushort_t* wqkvb = h1b + (size_t)M * HIDP;
    ushort_t* wob  = wqkvb + 3 * KP * KP;
    ushort_t* w1b  = wob + KP * KP;          // [HIDP][KP]
    ushort_t* w2b  = w1b + (size_t)HIDP * KP;// [KP][HIDP]
    float* nodesF  = (float*)(w2b + (size_t)KP * HIDP);  // [M][HSZ] final f32

    // attn-phase aliases inside h1b (dead until W1)
    ushort_t* qh  = h1b;                     // [bh][512][128]
    ushort_t* kh  = h1b + SP;
    ushort_t* vTb = h1b + 2 * SP;            // [bh][128][512]

    unsigned int* abits = (unsigned int*)d_out;  // overwritten by finalize_k

    build_nodes_k<<<BB * NNODES, 256, 0, stream>>>(ent_vec, entity_num, rels, rel_embed, Xb);
    adj_bits_k<<<(BB * NNODES * NNODES) / 64 / 4, 256, 0, stream>>>(adj, abits);

    for (int l = 0; l < NLAYER; ++l) {
        const float* bq_l = bq + (size_t)l * HSZ;
        const float* bk_l = bk + (size_t)l * HSZ;
        const float* bv_l = bv + (size_t)l * HSZ;
        const float* bo_l = bo + (size_t)l * HSZ;
        const float* b1_l = b1 + (size_t)l * HID;
        const float* b2_l = b2 + (size_t)l * HSZ;
        const float* pa_l = pa + (size_t)l * HID;

        wcvt_all_k<<<12288, 256, 0, stream>>>(
            Wq + (size_t)l * HSZ * HSZ, Wk + (size_t)l * HSZ * HSZ,
            Wv + (size_t)l * HSZ * HSZ, Wo + (size_t)l * HSZ * HSZ,
            W1 + (size_t)l * HSZ * HID, W2 + (size_t)l * HID * HSZ,
            wqkvb, wob, w1b, w2b);

        // fused QKV: writes qh, kh, and vT (transposed scatter) directly
        dim3 gQKV(1536 / 128, M / 128);  // (12, 128)
        gemm_mfma_k<<<gQKV, 256, 0, stream>>>(Xb, wqkvb, bq_l, bk_l, bv_l,
                                              qh, kh, vTb,
                                              M, 1536, KP, HSZ, nullptr, 1);

        attn_mfma_k<<<BB * NHEADS_ * 4, 256, 0, stream>>>(qh, kh, vTb, abits, ctxb);

        dim3 gO(KP / 128, M / 128);      // (4, 128)
        gemm_mfma_k<<<gO, 256, 0, stream>>>(ctxb, wob, bo_l, nullptr, nullptr,
                                            ob, nullptr, nullptr,
                                            M, KP, KP, HSZ, nullptr, 0);
        ln_k<<<M, 256, 0, stream>>>(ob, nullptr,
                                    ln1g + (size_t)l * HSZ, ln1b + (size_t)l * HSZ,
                                    tb, nullptr);

        // FFN un-chunked: one W1 (M x 2048), one W2 (M x 512)
        dim3 g1(HIDP / 128, M / 128);    // (16, 128)
        gemm_mfma_k<<<g1, 256, 0, stream>>>(tb, w1b, b1_l, nullptr, nullptr,
                                            h1b, nullptr, nullptr,
                                            M, HIDP, KP, HID, pa_l, 0);
        dim3 g2(KP / 128, M / 128);      // (4, 128)
        gemm_mfma_k<<<g2, 256, 0, stream>>>(h1b, w2b, b2_l, nullptr, nullptr,
                                            fb, nullptr, nullptr,
                                            M, KP, HIDP, HSZ, nullptr, 0);

        ln_k<<<M, 256, 0, stream>>>(fb, tb,
                                    ln2g + (size_t)l * HSZ, ln2b + (size_t)l * HSZ,
                                    Xb, (l == NLAYER - 1) ? nodesF : nullptr);
    }

    finalize_k<<<BB * NNODES, 256, 0, stream>>>(nodesF, entity_num, (float*)d_out);
}

// Round 11
// 560.721 us; speedup vs baseline: 1.3663x; 1.0103x over previous
//
#include <hip/hip_runtime.h>

#define BB 32
#define MEE 384
#define RRELS 128
#define NNODES 512
#define HSZ 500
#define DHEAD 125
#define NHEADS_ 4
#define HID 2000
#define NLAYER 2

#define KP 512      // padded HSZ
#define HIDP 2048   // padded HID

typedef unsigned short ushort_t;
typedef __attribute__((ext_vector_type(8))) short bf16x8;
typedef __attribute__((ext_vector_type(4))) float f32x4;
typedef __attribute__((ext_vector_type(4))) short s16x4;

static __device__ __forceinline__ unsigned short f2bf(float x) {
    unsigned u = __float_as_uint(x);
    u = u + 0x7fff + ((u >> 16) & 1);   // round-to-nearest-even
    return (unsigned short)(u >> 16);
}
static __device__ __forceinline__ float bf2f(unsigned short b) {
    return __uint_as_float((unsigned)b << 16);
}

static __device__ __forceinline__ void gload_lds16(const ushort_t* g, ushort_t* l) {
    __builtin_amdgcn_global_load_lds(
        (const __attribute__((address_space(1))) void*)g,
        (__attribute__((address_space(3))) void*)l, 16, 0, 0);
}

// ======================= build nodes (bf16-padded) =======================
__global__ __launch_bounds__(256) void build_nodes_k(
    const float* __restrict__ ent_vec, const int* __restrict__ entity_num,
    const int* __restrict__ rels, const float* __restrict__ rel_embed,
    ushort_t* __restrict__ xb)
{
    int b = blockIdx.x / NNODES;
    int n = blockIdx.x % NNODES;
    int e = entity_num[b];
    const float* src = nullptr;
    if (n < e)               src = ent_vec + ((size_t)b * MEE + n) * HSZ;
    else if (n < e + RRELS)  src = rel_embed + (size_t)rels[b * RRELS + (n - e)] * HSZ;
    ushort_t* xd = xb + ((size_t)b * NNODES + n) * KP;
    for (int d = threadIdx.x; d < KP; d += 256)
        xd[d] = (src && d < HSZ) ? f2bf(src[d]) : 0;
}

// ======================= adjacency -> bitmask =======================
__global__ __launch_bounds__(256) void adj_bits_k(
    const int* __restrict__ adj, unsigned int* __restrict__ bits)
{
    int gw = (blockIdx.x * 256 + threadIdx.x) >> 6;
    int lane = threadIdx.x & 63;
    int v = adj[(size_t)gw * 64 + lane];
    unsigned long long mk = __ballot(v != 0);
    if (lane == 0)  bits[gw * 2]     = (unsigned int)mk;
    if (lane == 32) bits[gw * 2 + 1] = (unsigned int)(mk >> 32);
}

// ======================= all-weights convert: LDS-tiled transpose ==============
// 768 blocks: [0,192) wqkv, [192,256) wo, [256,512) w1, [512,768) w2
__global__ __launch_bounds__(256) void wcvt_t_k(
    const float* __restrict__ pWq, const float* __restrict__ pWk,
    const float* __restrict__ pWv, const float* __restrict__ pWo,
    const float* __restrict__ pW1, const float* __restrict__ pW2,
    ushort_t* __restrict__ wqkv, ushort_t* __restrict__ wo,
    ushort_t* __restrict__ w1, ushort_t* __restrict__ w2)
{
    __shared__ float T[64][65];
    int blk = blockIdx.x;
    const float* W; ushort_t* out; int Kr, Nr, Kpp, tt;
    if (blk < 192)      { int s = blk >> 6; W = s == 0 ? pWq : (s == 1 ? pWk : pWv);
                          out = wqkv + s * 262144; Kr = 500; Nr = 500; Kpp = 512; tt = blk & 63; }
    else if (blk < 256) { W = pWo; out = wo;  Kr = 500;  Nr = 500;  Kpp = 512;  tt = blk - 192; }
    else if (blk < 512) { W = pW1; out = w1;  Kr = 500;  Nr = 2000; Kpp = 512;  tt = blk - 256; }
    else                { W = pW2; out = w2;  Kr = 2000; Nr = 500;  Kpp = 2048; tt = blk - 512; }
    int ntk = Kpp >> 6;
    int tk = tt % ntk, tn = tt / ntk;
    int tid = threadIdx.x;
    // read 64x64 f32 tile, coalesced on n
#pragma unroll
    for (int p = 0; p < 4; ++p) {
        int kl = p * 16 + (tid >> 4);
        int k  = tk * 64 + kl;
        int nl = (tid & 15) * 4;
        int n  = tn * 64 + nl;
        float4 v = make_float4(0.f, 0.f, 0.f, 0.f);
        if (k < Kr) {
            if (n + 3 < Nr) v = *(const float4*)&W[(size_t)k * Nr + n];
            else {
                if (n     < Nr) v.x = W[(size_t)k * Nr + n];
                if (n + 1 < Nr) v.y = W[(size_t)k * Nr + n + 1];
                if (n + 2 < Nr) v.z = W[(size_t)k * Nr + n + 2];
                if (n + 3 < Nr) v.w = W[(size_t)k * Nr + n + 3];
            }
        }
        T[kl][nl] = v.x; T[kl][nl + 1] = v.y; T[kl][nl + 2] = v.z; T[kl][nl + 3] = v.w;
    }
    __syncthreads();
    // write 64x64 bf16 transposed, coalesced on k
#pragma unroll
    for (int p = 0; p < 2; ++p) {
        int nl  = p * 32 + (tid >> 3);
        int kl8 = (tid & 7) * 8;
        bf16x8 o;
#pragma unroll
        for (int j = 0; j < 8; ++j) o[j] = (short)f2bf(T[kl8 + j][nl]);
        *(bf16x8*)&out[(size_t)(tn * 64 + nl) * Kpp + tk * 64 + kl8] = o;
    }
}

// ======================= bf16 MFMA GEMM (128x128, BK=32, 2-phase dbuf) ==========
// A: [M, Kp] bf16. Bt: [Np, Kp] bf16 (W^T).
// mode 0: outB = bf16 [M, Np], zero-padded cols, optional PReLU; LDS-staged
//         coalesced epilogue.
// mode 1: fused QKV, Np=1536: region 0->outB(qh), 1->outK(kh),
//         2->outV = V^T [bh][128][512] (scatter, s16x4)
__global__ __launch_bounds__(256, 2) void gemm_mfma_k(
    const ushort_t* __restrict__ A, const ushort_t* __restrict__ Bt,
    const float* __restrict__ bias0, const float* __restrict__ bias1,
    const float* __restrict__ bias2,
    ushort_t* __restrict__ outB, ushort_t* __restrict__ outK,
    ushort_t* __restrict__ outV,
    int M, int Np, int Kp, int Nreal,
    const float* __restrict__ prelu, int mode)
{
    __shared__ ushort_t Al[2][128 * 32];
    __shared__ ushort_t Bl[2][128 * 32];

    // bijective XCD-chunked swizzle (all grids have nwg % 8 == 0)
    const int nwg = gridDim.x * gridDim.y;
    const int bid = blockIdx.y * gridDim.x + blockIdx.x;
    const int swz = (bid & 7) * (nwg >> 3) + (bid >> 3);
    const int bm = (swz / gridDim.x) * 128;
    const int bn = (swz % gridDim.x) * 128;

    const int tid = threadIdx.x;
    const int wid = tid >> 6, lane = tid & 63;
    const int wr = wid >> 1, wc = wid & 1;
    const int lr = lane & 15, lk = lane >> 4;

    f32x4 acc[4][4];
#pragma unroll
    for (int i = 0; i < 4; ++i)
#pragma unroll
        for (int j = 0; j < 4; ++j)
#pragma unroll
            for (int r = 0; r < 4; ++r) acc[i][j][r] = 0.f;

    const int srow = tid >> 2;
    const int skseg = (tid & 3) * 8;
    const ushort_t* Ag0 = A + (size_t)(bm + srow) * Kp + skseg;
    const ushort_t* Ag1 = A + (size_t)(bm + 64 + srow) * Kp + skseg;
    const ushort_t* Bg0 = Bt + (size_t)(bn + srow) * Kp + skseg;
    const ushort_t* Bg1 = Bt + (size_t)(bn + 64 + srow) * Kp + skseg;

    auto stage = [&](int bi, int k0) {
        gload_lds16(Ag0 + k0, &Al[bi][wid * 512]);
        gload_lds16(Ag1 + k0, &Al[bi][2048 + wid * 512]);
        gload_lds16(Bg0 + k0, &Bl[bi][wid * 512]);
        gload_lds16(Bg1 + k0, &Bl[bi][2048 + wid * 512]);
    };

    stage(0, 0);
    __syncthreads();
    int cur = 0;

    for (int k0 = 0; k0 < Kp; k0 += 32) {
        if (k0 + 32 < Kp) stage(cur ^ 1, k0 + 32);   // prefetch under compute

        bf16x8 af[4], bfr[4];
#pragma unroll
        for (int mi = 0; mi < 4; ++mi)
            af[mi] = *(const bf16x8*)&Al[cur][(wr * 64 + mi * 16 + lr) * 32 + lk * 8];
#pragma unroll
        for (int ni = 0; ni < 4; ++ni)
            bfr[ni] = *(const bf16x8*)&Bl[cur][(wc * 64 + ni * 16 + lr) * 32 + lk * 8];
        __builtin_amdgcn_s_setprio(1);
#pragma unroll
        for (int mi = 0; mi < 4; ++mi)
#pragma unroll
            for (int ni = 0; ni < 4; ++ni)
                acc[mi][ni] = __builtin_amdgcn_mfma_f32_16x16x32_bf16(
                    af[mi], bfr[ni], acc[mi][ni], 0, 0, 0);
        __builtin_amdgcn_s_setprio(0);

        __syncthreads();   // drains prefetch + releases cur buffer
        cur ^= 1;
    }

    if (mode == 1) {
#pragma unroll
        for (int ni = 0; ni < 4; ++ni) {
            int col = bn + wc * 64 + ni * 16 + lr;
            int reg = col >> 9, c = col & 511;
            bool cok = c < 500;
            int hh, dh;
            if (cok) { hh = c / 125; dh = c - hh * 125; }
            else     { hh = (c - 500) / 3; dh = 125 + (c - 500) % 3; }
            const float* bp = reg == 0 ? bias0 : (reg == 1 ? bias1 : bias2);
            float bv = cok ? bp[c] : 0.f;
#pragma unroll
            for (int mi = 0; mi < 4; ++mi) {
                int row0 = bm + wr * 64 + mi * 16 + lk * 4;
                int b_ = row0 >> 9, n0 = row0 & 511;
                size_t bh = (size_t)b_ * 4 + hh;
                if (reg == 2) {
                    s16x4 pk;
#pragma unroll
                    for (int r = 0; r < 4; ++r) {
                        float val = acc[mi][ni][r] + bv;
                        pk[r] = cok ? (short)f2bf(val) : (short)0;
                    }
                    *(s16x4*)&outV[(bh * 128 + dh) * 512 + n0] = pk;
                } else {
                    ushort_t* dst = reg == 0 ? outB : outK;
#pragma unroll
                    for (int r = 0; r < 4; ++r) {
                        float val = acc[mi][ni][r] + bv;
                        dst[(bh * 512 + n0 + r) * 128 + dh] = cok ? f2bf(val) : 0;
                    }
                }
            }
        }
    } else {
        // LDS-staged coalesced epilogue: two 64-row halves through Al's 16KB
        ushort_t* Cst = &Al[0][0];   // 8192 ushort = 64 x 128
#pragma unroll
        for (int half = 0; half < 2; ++half) {
            __syncthreads();
            if (wr == half) {
#pragma unroll
                for (int ni = 0; ni < 4; ++ni) {
                    int col = wc * 64 + ni * 16 + lr;
                    int gcol = bn + col;
                    bool cok = gcol < Nreal;
                    float bv = cok ? bias0[gcol] : 0.f;
                    float pv = (prelu && cok) ? prelu[gcol] : 0.f;
                    int ch = col >> 3, cl = col & 7;
#pragma unroll
                    for (int mi = 0; mi < 4; ++mi) {
#pragma unroll
                        for (int r = 0; r < 4; ++r) {
                            int row = mi * 16 + lk * 4 + r;
                            float val = acc[mi][ni][r] + bv;
                            if (prelu) val = val > 0.f ? val : pv * val;
                            Cst[row * 128 + ((ch ^ (row & 7)) << 3) + cl] = cok ? f2bf(val) : 0;
                        }
                    }
                }
            }
            __syncthreads();
#pragma unroll
            for (int p = 0; p < 4; ++p) {
                int row = p * 16 + (tid >> 4);
                int c = tid & 15;
                bf16x8 v = *(const bf16x8*)&Cst[row * 128 + ((c ^ (row & 7)) << 3)];
                *(bf16x8*)&outB[(size_t)(bm + half * 64 + row) * Np + bn + c * 8] = v;
            }
        }
    }
}

// ======================= MFMA flash attention v2 (unchanged) ====================
#define KTT 64
__global__ __launch_bounds__(256, 2) void attn_mfma_k(
    const ushort_t* __restrict__ qh, const ushort_t* __restrict__ kh,
    const ushort_t* __restrict__ vT, const unsigned int* __restrict__ abits,
    ushort_t* __restrict__ ctxb)
{
    __shared__ ushort_t Kl[2][KTT * 128];    // 2 x 16KB
    __shared__ ushort_t Vl[2][128 * KTT];    // 2 x 16KB
    __shared__ ushort_t Pl[4][32 * KTT];     // 16KB

    const int bid = blockIdx.x;
    const int wg = (bid & 7) * 64 + (bid >> 3);   // 512 wgs: chunked XCD swizzle
    const int qt2 = wg & 3, bh = wg >> 2;
    const int b = bh >> 2, h = bh & 3;
    const int tid = threadIdx.x, wid = tid >> 6, lane = tid & 63;
    const int lr = lane & 15, lk = lane >> 4;
    const int q0 = qt2 * 128 + wid * 32;          // wave's 32 q rows
    const float scale = 0.08944271909999159f;     // 1/sqrt(125)

    bf16x8 qa[2][4];
#pragma unroll
    for (int t = 0; t < 2; ++t) {
        const ushort_t* qbase = qh + ((size_t)bh * 512 + q0 + t * 16 + lr) * 128;
#pragma unroll
        for (int ks = 0; ks < 4; ++ks)
            qa[t][ks] = *(const bf16x8*)&qbase[ks * 32 + lk * 8];
    }

    f32x4 accO[2][8];
#pragma unroll
    for (int t = 0; t < 2; ++t)
#pragma unroll
        for (int i = 0; i < 8; ++i)
#pragma unroll
            for (int r = 0; r < 4; ++r) accO[t][i][r] = 0.f;
    float m_[2][4], l_[2][4];
#pragma unroll
    for (int t = 0; t < 2; ++t)
#pragma unroll
        for (int r = 0; r < 4; ++r) { m_[t][r] = -3e38f; l_[t][r] = 0.f; }

    const unsigned int* ab = abits + ((size_t)b * NNODES + q0) * 16;

    auto stage = [&](int bi, int kt) {
#pragma unroll
        for (int i = 0; i < 4; ++i) {
            int linear = (wid * 4 + i) * 64 + lane;
            int row = linear >> 4, cc = linear & 15;
            int cs = cc ^ (row & 7);
            gload_lds16(kh + ((size_t)bh * 512 + kt * 64 + row) * 128 + cs * 8,
                        &Kl[bi][(wid * 4 + i) * 512]);
        }
#pragma unroll
        for (int i = 0; i < 4; ++i) {
            int linear = (wid * 4 + i) * 64 + lane;
            int row = linear >> 3, cc = linear & 7;
            int cs = cc ^ (row & 7);
            gload_lds16(vT + ((size_t)bh * 128 + row) * 512 + kt * 64 + cs * 8,
                        &Vl[bi][(wid * 4 + i) * 512]);
        }
    };

    stage(0, 0);
    __syncthreads();
    int cur = 0;

    for (int kt = 0; kt < NNODES / KTT; ++kt) {
        if (kt < NNODES / KTT - 1) stage(cur ^ 1, kt + 1);  // prefetch under compute

        unsigned int mw[2][4][2];
#pragma unroll
        for (int t = 0; t < 2; ++t)
#pragma unroll
            for (int r = 0; r < 4; ++r) {
                int qrow = t * 16 + lk * 4 + r;
                mw[t][r][0] = ab[qrow * 16 + kt * 2];
                mw[t][r][1] = ab[qrow * 16 + kt * 2 + 1];
            }

#pragma unroll
        for (int t = 0; t < 2; ++t) {
            f32x4 accS[4];
#pragma unroll
            for (int ni = 0; ni < 4; ++ni)
#pragma unroll
                for (int r = 0; r < 4; ++r) accS[ni][r] = 0.f;
            __builtin_amdgcn_s_setprio(1);
#pragma unroll
            for (int ks = 0; ks < 4; ++ks) {
#pragma unroll
                for (int ni = 0; ni < 4; ++ni) {
                    int row = ni * 16 + lr;
                    int ch = (ks * 4 + lk) ^ (row & 7);
                    bf16x8 kb = *(const bf16x8*)&Kl[cur][row * 128 + ch * 8];
                    accS[ni] = __builtin_amdgcn_mfma_f32_16x16x32_bf16(
                        qa[t][ks], kb, accS[ni], 0, 0, 0);
                }
            }
            __builtin_amdgcn_s_setprio(0);
#pragma unroll
            for (int r = 0; r < 4; ++r) {
                float s[4];
#pragma unroll
                for (int ni = 0; ni < 4; ++ni) {
                    unsigned int word = mw[t][r][ni >> 1];
                    int bit = (ni & 1) * 16 + lr;
                    bool on = (word >> bit) & 1u;
                    s[ni] = on ? accS[ni][r] * scale : -1e9f;
                }
                float rowmax = fmaxf(fmaxf(s[0], s[1]), fmaxf(s[2], s[3]));
                rowmax = fmaxf(rowmax, __shfl_xor(rowmax, 1));
                rowmax = fmaxf(rowmax, __shfl_xor(rowmax, 2));
                rowmax = fmaxf(rowmax, __shfl_xor(rowmax, 4));
                rowmax = fmaxf(rowmax, __shfl_xor(rowmax, 8));
                float mnew = fmaxf(m_[t][r], rowmax);
                float f = __expf(m_[t][r] - mnew);
                m_[t][r] = mnew;
                float p[4], rs = 0.f;
#pragma unroll
                for (int ni = 0; ni < 4; ++ni) { p[ni] = __expf(s[ni] - mnew); rs += p[ni]; }
                rs += __shfl_xor(rs, 1);
                rs += __shfl_xor(rs, 2);
                rs += __shfl_xor(rs, 4);
                rs += __shfl_xor(rs, 8);
                l_[t][r] = l_[t][r] * f + rs;
#pragma unroll
                for (int di = 0; di < 8; ++di) accO[t][di][r] *= f;
                int q = t * 16 + lk * 4 + r;
#pragma unroll
                for (int ni = 0; ni < 4; ++ni) {
                    int key = ni * 16 + lr;
                    Pl[wid][q * 64 + (((key >> 3) ^ (q & 7)) << 3) + (key & 7)] = f2bf(p[ni]);
                }
            }
        }

#pragma unroll
        for (int t = 0; t < 2; ++t) {
#pragma unroll
            for (int ksp = 0; ksp < 2; ++ksp) {
                int q = t * 16 + lr;
                int k0p = ksp * 32 + lk * 8;
                bf16x8 pa = *(const bf16x8*)&Pl[wid][q * 64 + (((k0p >> 3) ^ (q & 7)) << 3)];
                __builtin_amdgcn_s_setprio(1);
#pragma unroll
                for (int di = 0; di < 8; ++di) {
                    int row = di * 16 + lr;
                    int ch = (ksp * 4 + lk) ^ (row & 7);
                    bf16x8 vb = *(const bf16x8*)&Vl[cur][row * 64 + ch * 8];
                    accO[t][di] = __builtin_amdgcn_mfma_f32_16x16x32_bf16(
                        pa, vb, accO[t][di], 0, 0, 0);
                }
                __builtin_amdgcn_s_setprio(0);
            }
        }
        __syncthreads();
        cur ^= 1;
    }

    float inv[2][4];
#pragma unroll
    for (int t = 0; t < 2; ++t)
#pragma unroll
        for (int r = 0; r < 4; ++r) inv[t][r] = 1.f / l_[t][r];
#pragma unroll
    for (int t = 0; t < 2; ++t)
#pragma unroll
        for (int di = 0; di < 8; ++di) {
            int d = di * 16 + lr;
            if (d < DHEAD) {
#pragma unroll
                for (int r = 0; r < 4; ++r) {
                    int qg = q0 + t * 16 + lk * 4 + r;
                    ctxb[((size_t)b * NNODES + qg) * KP + h * DHEAD + d] =
                        f2bf(accO[t][di][r] * inv[t][r]);
                }
            }
        }
    if (h == 3) {
        int row = q0 + (lane & 31);
        int c0 = 500 + (lane >> 5) * 6;
#pragma unroll
        for (int j = 0; j < 6; ++j)
            ctxb[((size_t)b * NNODES + row) * KP + c0 + j] = 0;
    }
}

// ======================= layernorm bf16->bf16 (optional residual) ==============
__global__ __launch_bounds__(256) void ln_k(
    const ushort_t* __restrict__ x, const ushort_t* __restrict__ res,
    const float* __restrict__ g, const float* __restrict__ bta,
    ushort_t* __restrict__ outB)
{
    size_t row = blockIdx.x;
    const unsigned int* xr = (const unsigned int*)(x + row * KP);
    const unsigned int* rr = res ? (const unsigned int*)(res + row * KP) : nullptr;
    int t = threadIdx.x;           // thread t handles dims 2t, 2t+1
    int d0 = 2 * t;
    unsigned int xv = xr[t];
    float v0 = bf2f((unsigned short)(xv & 0xffff));
    float v1 = bf2f((unsigned short)(xv >> 16));
    if (rr) {
        unsigned int rv = rr[t];
        v0 += bf2f((unsigned short)(rv & 0xffff));
        v1 += bf2f((unsigned short)(rv >> 16));
    }
    if (d0 >= HSZ) v0 = 0.f;
    if (d0 + 1 >= HSZ) v1 = 0.f;
    float s = v0 + v1, s2 = v0 * v0 + v1 * v1;

    __shared__ float red[8];
    int wave = t >> 6, lane = t & 63;
    for (int o = 1; o < 64; o <<= 1) { s += __shfl_xor(s, o); s2 += __shfl_xor(s2, o); }
    if (lane == 0) { red[wave] = s; red[4 + wave] = s2; }
    __syncthreads();
    s  = red[0] + red[1] + red[2] + red[3];
    s2 = red[4] + red[5] + red[6] + red[7];
    float mean = s / HSZ;
    float var  = s2 / HSZ - mean * mean;
    float rstd = rsqrtf(var + 1e-5f);

    float o0 = 0.f, o1 = 0.f;
    if (d0 < HSZ)     o0 = (v0 - mean) * rstd * g[d0] + bta[d0];
    if (d0 + 1 < HSZ) o1 = (v1 - mean) * rstd * g[d0 + 1] + bta[d0 + 1];
    unsigned int pk = (unsigned int)f2bf(o0) | ((unsigned int)f2bf(o1) << 16);
    if (d0 >= HSZ) pk = 0;
    else if (d0 + 1 >= HSZ) pk = (unsigned int)f2bf(o0);
    ((unsigned int*)(outB + row * KP))[t] = pk;
}

// ======================= finalize (reads bf16 nodes): glob, node_emb, mask =====
__global__ __launch_bounds__(256) void finalize_k(
    const ushort_t* __restrict__ nodes, const int* __restrict__ entity_num,
    float* __restrict__ out)
{
    int b = blockIdx.x / NNODES;
    int n = blockIdx.x % NNODES;
    int e = entity_num[b];
    int size = e + RRELS;
    const ushort_t* src = nodes + ((size_t)b * NNODES + n) * KP;
    float* ne = out + (size_t)BB * HSZ + ((size_t)b * NNODES + n) * HSZ;
    bool valid = n < size;
    for (int d = threadIdx.x; d < HSZ; d += 256) ne[d] = valid ? bf2f(src[d]) : 0.f;
    if (n == e) {
        float* gl = out + (size_t)b * HSZ;
        for (int d = threadIdx.x; d < HSZ; d += 256) gl[d] = bf2f(src[d]);
    }
    if (threadIdx.x == 0) {
        out[(size_t)BB * HSZ + (size_t)BB * NNODES * HSZ + (size_t)b * NNODES + n] =
            (n <= size) ? 1.f : 0.f;
    }
}

// ======================= host =======================
extern "C" void kernel_launch(void* const* d_in, const int* in_sizes, int n_in,
                              void* d_out, int out_size, void* d_ws, size_t ws_size,
                              hipStream_t stream)
{
    const float* ent_vec    = (const float*)d_in[0];
    const int*   entity_num = (const int*)d_in[1];
    const int*   rels       = (const int*)d_in[2];
    const int*   adj        = (const int*)d_in[3];
    const float* rel_embed  = (const float*)d_in[4];
    const float* Wq = (const float*)d_in[5],  *bq = (const float*)d_in[6];
    const float* Wk = (const float*)d_in[7],  *bk = (const float*)d_in[8];
    const float* Wv = (const float*)d_in[9],  *bv = (const float*)d_in[10];
    const float* Wo = (const float*)d_in[11], *bo = (const float*)d_in[12];
    const float* W1 = (const float*)d_in[13], *b1 = (const float*)d_in[14];
    const float* W2 = (const float*)d_in[15], *b2 = (const float*)d_in[16];
    const float* ln1g = (const float*)d_in[17], *ln1b = (const float*)d_in[18];
    const float* ln2g = (const float*)d_in[19], *ln2b = (const float*)d_in[20];
    const float* pa = (const float*)d_in[21];

    const int M = BB * NNODES;               // 16384
    const size_t SP = (size_t)M * KP;        // 8,388,608 bf16

    ushort_t* Xb   = (ushort_t*)d_ws;        // [M][KP]  nodes bf16
    ushort_t* ctxb = Xb + SP;                // attention context
    ushort_t* tb   = ctxb + SP;              // t (ln1 out)
    ushort_t* ob   = tb + SP;                // o (O-proj out)
    ushort_t* fb   = ob + SP;                // f (W2 out)
    ushort_t* h1b  = fb + SP;                // [16384][2048] h1 (67.1MB)
    ushort_t* wqkvb = h1b + (size_t)M * HIDP;
    ushort_t* wob  = wqkvb + 3 * KP * KP;
    ushort_t* w1b  = wob + KP * KP;          // [HIDP][KP]
    ushort_t* w2b  = w1b + (size_t)HIDP * KP;// [KP][HIDP]

    // attn-phase aliases inside h1b (dead until W1)
    ushort_t* qh  = h1b;                     // [bh][512][128]
    ushort_t* kh  = h1b + SP;
    ushort_t* vTb = h1b + 2 * SP;            // [bh][128][512]

    unsigned int* abits = (unsigned int*)d_out;  // overwritten by finalize_k

    build_nodes_k<<<BB * NNODES, 256, 0, stream>>>(ent_vec, entity_num, rels, rel_embed, Xb);
    adj_bits_k<<<(BB * NNODES * NNODES) / 64 / 4, 256, 0, stream>>>(adj, abits);

    for (int l = 0; l < NLAYER; ++l) {
        const float* bq_l = bq + (size_t)l * HSZ;
        const float* bk_l = bk + (size_t)l * HSZ;
        const float* bv_l = bv + (size_t)l * HSZ;
        const float* bo_l = bo + (size_t)l * HSZ;
        const float* b1_l = b1 + (size_t)l * HID;
        const float* b2_l = b2 + (size_t)l * HSZ;
        const float* pa_l = pa + (size_t)l * HID;

        wcvt_t_k<<<768, 256, 0, stream>>>(
            Wq + (size_t)l * HSZ * HSZ, Wk + (size_t)l * HSZ * HSZ,
            Wv + (size_t)l * HSZ * HSZ, Wo + (size_t)l * HSZ * HSZ,
            W1 + (size_t)l * HSZ * HID, W2 + (size_t)l * HID * HSZ,
            wqkvb, wob, w1b, w2b);

        // fused QKV: writes qh, kh, and vT (transposed scatter) directly
        dim3 gQKV(1536 / 128, M / 128);  // (12, 128)
        gemm_mfma_k<<<gQKV, 256, 0, stream>>>(Xb, wqkvb, bq_l, bk_l, bv_l,
                                              qh, kh, vTb,
                                              M, 1536, KP, HSZ, nullptr, 1);

        attn_mfma_k<<<BB * NHEADS_ * 4, 256, 0, stream>>>(qh, kh, vTb, abits, ctxb);

        dim3 gO(KP / 128, M / 128);      // (4, 128)
        gemm_mfma_k<<<gO, 256, 0, stream>>>(ctxb, wob, bo_l, nullptr, nullptr,
                                            ob, nullptr, nullptr,
                                            M, KP, KP, HSZ, nullptr, 0);
        ln_k<<<M, 256, 0, stream>>>(ob, nullptr,
                                    ln1g + (size_t)l * HSZ, ln1b + (size_t)l * HSZ,
                                    tb);

        // FFN un-chunked: one W1 (M x 2048), one W2 (M x 512)
        dim3 g1(HIDP / 128, M / 128);    // (16, 128)
        gemm_mfma_k<<<g1, 256, 0, stream>>>(tb, w1b, b1_l, nullptr, nullptr,
                                            h1b, nullptr, nullptr,
                                            M, HIDP, KP, HID, pa_l, 0);
        dim3 g2(KP / 128, M / 128);      // (4, 128)
        gemm_mfma_k<<<g2, 256, 0, stream>>>(h1b, w2b, b2_l, nullptr, nullptr,
                                            fb, nullptr, nullptr,
                                            M, KP, HIDP, HSZ, nullptr, 0);

        ln_k<<<M, 256, 0, stream>>>(fb, tb,
                                    ln2g + (size_t)l * HSZ, ln2b + (size_t)l * HSZ,
                                    Xb);
    }

    finalize_k<<<BB * NNODES, 256, 0, stream>>>(Xb, entity_num, (float*)d_out);
}

// Round 12
// 530.720 us; speedup vs baseline: 1.4435x; 1.0565x over previous
//
#include <hip/hip_runtime.h>

#define BB 32
#define MEE 384
#define RRELS 128
#define NNODES 512
#define HSZ 500
#define DHEAD 125
#define NHEADS_ 4
#define HID 2000
#define NLAYER 2

#define KP 512      // padded HSZ
#define HIDP 2048   // padded HID

typedef unsigned short ushort_t;
typedef __attribute__((ext_vector_type(8))) short bf16x8;
typedef __attribute__((ext_vector_type(4))) float f32x4;
typedef __attribute__((ext_vector_type(4))) short s16x4;

static __device__ __forceinline__ unsigned short f2bf(float x) {
    unsigned u = __float_as_uint(x);
    u = u + 0x7fff + ((u >> 16) & 1);   // round-to-nearest-even
    return (unsigned short)(u >> 16);
}
static __device__ __forceinline__ float bf2f(unsigned short b) {
    return __uint_as_float((unsigned)b << 16);
}

static __device__ __forceinline__ void gload_lds16(const ushort_t* g, ushort_t* l) {
    __builtin_amdgcn_global_load_lds(
        (const __attribute__((address_space(1))) void*)g,
        (__attribute__((address_space(3))) void*)l, 16, 0, 0);
}

// ======================= build nodes (bf16-padded) =======================
__global__ __launch_bounds__(256) void build_nodes_k(
    const float* __restrict__ ent_vec, const int* __restrict__ entity_num,
    const int* __restrict__ rels, const float* __restrict__ rel_embed,
    ushort_t* __restrict__ xb)
{
    int b = blockIdx.x / NNODES;
    int n = blockIdx.x % NNODES;
    int e = entity_num[b];
    const float* src = nullptr;
    if (n < e)               src = ent_vec + ((size_t)b * MEE + n) * HSZ;
    else if (n < e + RRELS)  src = rel_embed + (size_t)rels[b * RRELS + (n - e)] * HSZ;
    ushort_t* xd = xb + ((size_t)b * NNODES + n) * KP;
    for (int d = threadIdx.x; d < KP; d += 256)
        xd[d] = (src && d < HSZ) ? f2bf(src[d]) : 0;
}

// ======================= adjacency -> bitmask =======================
__global__ __launch_bounds__(256) void adj_bits_k(
    const int* __restrict__ adj, unsigned int* __restrict__ bits)
{
    int gw = (blockIdx.x * 256 + threadIdx.x) >> 6;
    int lane = threadIdx.x & 63;
    int v = adj[(size_t)gw * 64 + lane];
    unsigned long long mk = __ballot(v != 0);
    if (lane == 0)  bits[gw * 2]     = (unsigned int)mk;
    if (lane == 32) bits[gw * 2 + 1] = (unsigned int)(mk >> 32);
}

// ======================= all-weights convert: LDS-tiled transpose ==============
// 768 blocks: [0,192) wqkv, [192,256) wo, [256,512) w1, [512,768) w2
__global__ __launch_bounds__(256) void wcvt_t_k(
    const float* __restrict__ pWq, const float* __restrict__ pWk,
    const float* __restrict__ pWv, const float* __restrict__ pWo,
    const float* __restrict__ pW1, const float* __restrict__ pW2,
    ushort_t* __restrict__ wqkv, ushort_t* __restrict__ wo,
    ushort_t* __restrict__ w1, ushort_t* __restrict__ w2)
{
    __shared__ float T[64][65];
    int blk = blockIdx.x;
    const float* W; ushort_t* out; int Kr, Nr, Kpp, tt;
    if (blk < 192)      { int s = blk >> 6; W = s == 0 ? pWq : (s == 1 ? pWk : pWv);
                          out = wqkv + s * 262144; Kr = 500; Nr = 500; Kpp = 512; tt = blk & 63; }
    else if (blk < 256) { W = pWo; out = wo;  Kr = 500;  Nr = 500;  Kpp = 512;  tt = blk - 192; }
    else if (blk < 512) { W = pW1; out = w1;  Kr = 500;  Nr = 2000; Kpp = 512;  tt = blk - 256; }
    else                { W = pW2; out = w2;  Kr = 2000; Nr = 500;  Kpp = 2048; tt = blk - 512; }
    int ntk = Kpp >> 6;
    int tk = tt % ntk, tn = tt / ntk;
    int tid = threadIdx.x;
    // read 64x64 f32 tile, coalesced on n
#pragma unroll
    for (int p = 0; p < 4; ++p) {
        int kl = p * 16 + (tid >> 4);
        int k  = tk * 64 + kl;
        int nl = (tid & 15) * 4;
        int n  = tn * 64 + nl;
        float4 v = make_float4(0.f, 0.f, 0.f, 0.f);
        if (k < Kr) {
            if (n + 3 < Nr) v = *(const float4*)&W[(size_t)k * Nr + n];
            else {
                if (n     < Nr) v.x = W[(size_t)k * Nr + n];
                if (n + 1 < Nr) v.y = W[(size_t)k * Nr + n + 1];
                if (n + 2 < Nr) v.z = W[(size_t)k * Nr + n + 2];
                if (n + 3 < Nr) v.w = W[(size_t)k * Nr + n + 3];
            }
        }
        T[kl][nl] = v.x; T[kl][nl + 1] = v.y; T[kl][nl + 2] = v.z; T[kl][nl + 3] = v.w;
    }
    __syncthreads();
    // write 64x64 bf16 transposed, coalesced on k
#pragma unroll
    for (int p = 0; p < 2; ++p) {
        int nl  = p * 32 + (tid >> 3);
        int kl8 = (tid & 7) * 8;
        bf16x8 o;
#pragma unroll
        for (int j = 0; j < 8; ++j) o[j] = (short)f2bf(T[kl8 + j][nl]);
        *(bf16x8*)&out[(size_t)(tn * 64 + nl) * Kpp + tk * 64 + kl8] = o;
    }
}

// ======================= bf16 MFMA GEMM (128x128, BK=32, 2-phase dbuf) ==========
// A: [M, Kp] bf16. Bt: [Np, Kp] bf16 (W^T).
// mode 0: outB = bf16 [M, Np], zero-padded cols, optional PReLU (direct stores)
// mode 1: fused QKV, Np=1536: region 0->outB(qh), 1->outK(kh),
//         2->outV = V^T [bh][128][512] (scatter, s16x4)
__global__ __launch_bounds__(256, 2) void gemm_mfma_k(
    const ushort_t* __restrict__ A, const ushort_t* __restrict__ Bt,
    const float* __restrict__ bias0, const float* __restrict__ bias1,
    const float* __restrict__ bias2,
    ushort_t* __restrict__ outB, ushort_t* __restrict__ outK,
    ushort_t* __restrict__ outV,
    int M, int Np, int Kp, int Nreal,
    const float* __restrict__ prelu, int mode)
{
    __shared__ ushort_t Al[2][128 * 32];
    __shared__ ushort_t Bl[2][128 * 32];

    // bijective XCD-chunked swizzle (all grids have nwg % 8 == 0)
    const int nwg = gridDim.x * gridDim.y;
    const int bid = blockIdx.y * gridDim.x + blockIdx.x;
    const int swz = (bid & 7) * (nwg >> 3) + (bid >> 3);
    const int bm = (swz / gridDim.x) * 128;
    const int bn = (swz % gridDim.x) * 128;

    const int tid = threadIdx.x;
    const int wid = tid >> 6, lane = tid & 63;
    const int wr = wid >> 1, wc = wid & 1;
    const int lr = lane & 15, lk = lane >> 4;

    f32x4 acc[4][4];
#pragma unroll
    for (int i = 0; i < 4; ++i)
#pragma unroll
        for (int j = 0; j < 4; ++j)
#pragma unroll
            for (int r = 0; r < 4; ++r) acc[i][j][r] = 0.f;

    const int srow = tid >> 2;
    const int skseg = (tid & 3) * 8;
    const ushort_t* Ag0 = A + (size_t)(bm + srow) * Kp + skseg;
    const ushort_t* Ag1 = A + (size_t)(bm + 64 + srow) * Kp + skseg;
    const ushort_t* Bg0 = Bt + (size_t)(bn + srow) * Kp + skseg;
    const ushort_t* Bg1 = Bt + (size_t)(bn + 64 + srow) * Kp + skseg;

    auto stage = [&](int bi, int k0) {
        gload_lds16(Ag0 + k0, &Al[bi][wid * 512]);
        gload_lds16(Ag1 + k0, &Al[bi][2048 + wid * 512]);
        gload_lds16(Bg0 + k0, &Bl[bi][wid * 512]);
        gload_lds16(Bg1 + k0, &Bl[bi][2048 + wid * 512]);
    };

    stage(0, 0);
    __syncthreads();
    int cur = 0;

    for (int k0 = 0; k0 < Kp; k0 += 32) {
        if (k0 + 32 < Kp) stage(cur ^ 1, k0 + 32);   // prefetch under compute

        bf16x8 af[4], bfr[4];
#pragma unroll
        for (int mi = 0; mi < 4; ++mi)
            af[mi] = *(const bf16x8*)&Al[cur][(wr * 64 + mi * 16 + lr) * 32 + lk * 8];
#pragma unroll
        for (int ni = 0; ni < 4; ++ni)
            bfr[ni] = *(const bf16x8*)&Bl[cur][(wc * 64 + ni * 16 + lr) * 32 + lk * 8];
        __builtin_amdgcn_s_setprio(1);
#pragma unroll
        for (int mi = 0; mi < 4; ++mi)
#pragma unroll
            for (int ni = 0; ni < 4; ++ni)
                acc[mi][ni] = __builtin_amdgcn_mfma_f32_16x16x32_bf16(
                    af[mi], bfr[ni], acc[mi][ni], 0, 0, 0);
        __builtin_amdgcn_s_setprio(0);

        __syncthreads();   // drains prefetch + releases cur buffer
        cur ^= 1;
    }

    if (mode == 1) {
#pragma unroll
        for (int ni = 0; ni < 4; ++ni) {
            int col = bn + wc * 64 + ni * 16 + lr;
            int reg = col >> 9, c = col & 511;
            bool cok = c < 500;
            int hh, dh;
            if (cok) { hh = c / 125; dh = c - hh * 125; }
            else     { hh = (c - 500) / 3; dh = 125 + (c - 500) % 3; }
            const float* bp = reg == 0 ? bias0 : (reg == 1 ? bias1 : bias2);
            float bv = cok ? bp[c] : 0.f;
#pragma unroll
            for (int mi = 0; mi < 4; ++mi) {
                int row0 = bm + wr * 64 + mi * 16 + lk * 4;
                int b_ = row0 >> 9, n0 = row0 & 511;
                size_t bh = (size_t)b_ * 4 + hh;
                if (reg == 2) {
                    s16x4 pk;
#pragma unroll
                    for (int r = 0; r < 4; ++r) {
                        float val = acc[mi][ni][r] + bv;
                        pk[r] = cok ? (short)f2bf(val) : (short)0;
                    }
                    *(s16x4*)&outV[(bh * 128 + dh) * 512 + n0] = pk;
                } else {
                    ushort_t* dst = reg == 0 ? outB : outK;
#pragma unroll
                    for (int r = 0; r < 4; ++r) {
                        float val = acc[mi][ni][r] + bv;
                        dst[(bh * 512 + n0 + r) * 128 + dh] = cok ? f2bf(val) : 0;
                    }
                }
            }
        }
    } else {
        // direct per-lane stores (measured faster than LDS-staged epilogue:
        // WRITE amplification is absorbed by L2 and is not the binding constraint)
#pragma unroll
        for (int ni = 0; ni < 4; ++ni) {
            int col = bn + wc * 64 + ni * 16 + lr;
            bool cok = col < Nreal;
            float bv = cok ? bias0[col] : 0.f;
            float pv = (prelu && cok) ? prelu[col] : 0.f;
#pragma unroll
            for (int mi = 0; mi < 4; ++mi) {
                int row0 = bm + wr * 64 + mi * 16 + lk * 4;
#pragma unroll
                for (int r = 0; r < 4; ++r) {
                    int row = row0 + r;
                    float val = acc[mi][ni][r] + bv;
                    if (prelu) val = val > 0.f ? val : pv * val;
                    outB[(size_t)row * Np + col] = cok ? f2bf(val) : 0;
                }
            }
        }
    }
}

// ======================= MFMA flash attention v2 (unchanged) ====================
#define KTT 64
__global__ __launch_bounds__(256, 2) void attn_mfma_k(
    const ushort_t* __restrict__ qh, const ushort_t* __restrict__ kh,
    const ushort_t* __restrict__ vT, const unsigned int* __restrict__ abits,
    ushort_t* __restrict__ ctxb)
{
    __shared__ ushort_t Kl[2][KTT * 128];    // 2 x 16KB
    __shared__ ushort_t Vl[2][128 * KTT];    // 2 x 16KB
    __shared__ ushort_t Pl[4][32 * KTT];     // 16KB

    const int bid = blockIdx.x;
    const int wg = (bid & 7) * 64 + (bid >> 3);   // 512 wgs: chunked XCD swizzle
    const int qt2 = wg & 3, bh = wg >> 2;
    const int b = bh >> 2, h = bh & 3;
    const int tid = threadIdx.x, wid = tid >> 6, lane = tid & 63;
    const int lr = lane & 15, lk = lane >> 4;
    const int q0 = qt2 * 128 + wid * 32;          // wave's 32 q rows
    const float scale = 0.08944271909999159f;     // 1/sqrt(125)

    bf16x8 qa[2][4];
#pragma unroll
    for (int t = 0; t < 2; ++t) {
        const ushort_t* qbase = qh + ((size_t)bh * 512 + q0 + t * 16 + lr) * 128;
#pragma unroll
        for (int ks = 0; ks < 4; ++ks)
            qa[t][ks] = *(const bf16x8*)&qbase[ks * 32 + lk * 8];
    }

    f32x4 accO[2][8];
#pragma unroll
    for (int t = 0; t < 2; ++t)
#pragma unroll
        for (int i = 0; i < 8; ++i)
#pragma unroll
            for (int r = 0; r < 4; ++r) accO[t][i][r] = 0.f;
    float m_[2][4], l_[2][4];
#pragma unroll
    for (int t = 0; t < 2; ++t)
#pragma unroll
        for (int r = 0; r < 4; ++r) { m_[t][r] = -3e38f; l_[t][r] = 0.f; }

    const unsigned int* ab = abits + ((size_t)b * NNODES + q0) * 16;

    auto stage = [&](int bi, int kt) {
#pragma unroll
        for (int i = 0; i < 4; ++i) {
            int linear = (wid * 4 + i) * 64 + lane;
            int row = linear >> 4, cc = linear & 15;
            int cs = cc ^ (row & 7);
            gload_lds16(kh + ((size_t)bh * 512 + kt * 64 + row) * 128 + cs * 8,
                        &Kl[bi][(wid * 4 + i) * 512]);
        }
#pragma unroll
        for (int i = 0; i < 4; ++i) {
            int linear = (wid * 4 + i) * 64 + lane;
            int row = linear >> 3, cc = linear & 7;
            int cs = cc ^ (row & 7);
            gload_lds16(vT + ((size_t)bh * 128 + row) * 512 + kt * 64 + cs * 8,
                        &Vl[bi][(wid * 4 + i) * 512]);
        }
    };

    stage(0, 0);
    __syncthreads();
    int cur = 0;

    for (int kt = 0; kt < NNODES / KTT; ++kt) {
        if (kt < NNODES / KTT - 1) stage(cur ^ 1, kt + 1);  // prefetch under compute

        unsigned int mw[2][4][2];
#pragma unroll
        for (int t = 0; t < 2; ++t)
#pragma unroll
            for (int r = 0; r < 4; ++r) {
                int qrow = t * 16 + lk * 4 + r;
                mw[t][r][0] = ab[qrow * 16 + kt * 2];
                mw[t][r][1] = ab[qrow * 16 + kt * 2 + 1];
            }

#pragma unroll
        for (int t = 0; t < 2; ++t) {
            f32x4 accS[4];
#pragma unroll
            for (int ni = 0; ni < 4; ++ni)
#pragma unroll
                for (int r = 0; r < 4; ++r) accS[ni][r] = 0.f;
            __builtin_amdgcn_s_setprio(1);
#pragma unroll
            for (int ks = 0; ks < 4; ++ks) {
#pragma unroll
                for (int ni = 0; ni < 4; ++ni) {
                    int row = ni * 16 + lr;
                    int ch = (ks * 4 + lk) ^ (row & 7);
                    bf16x8 kb = *(const bf16x8*)&Kl[cur][row * 128 + ch * 8];
                    accS[ni] = __builtin_amdgcn_mfma_f32_16x16x32_bf16(
                        qa[t][ks], kb, accS[ni], 0, 0, 0);
                }
            }
            __builtin_amdgcn_s_setprio(0);
#pragma unroll
            for (int r = 0; r < 4; ++r) {
                float s[4];
#pragma unroll
                for (int ni = 0; ni < 4; ++ni) {
                    unsigned int word = mw[t][r][ni >> 1];
                    int bit = (ni & 1) * 16 + lr;
                    bool on = (word >> bit) & 1u;
                    s[ni] = on ? accS[ni][r] * scale : -1e9f;
                }
                float rowmax = fmaxf(fmaxf(s[0], s[1]), fmaxf(s[2], s[3]));
                rowmax = fmaxf(rowmax, __shfl_xor(rowmax, 1));
                rowmax = fmaxf(rowmax, __shfl_xor(rowmax, 2));
                rowmax = fmaxf(rowmax, __shfl_xor(rowmax, 4));
                rowmax = fmaxf(rowmax, __shfl_xor(rowmax, 8));
                float mnew = fmaxf(m_[t][r], rowmax);
                float f = __expf(m_[t][r] - mnew);
                m_[t][r] = mnew;
                float p[4], rs = 0.f;
#pragma unroll
                for (int ni = 0; ni < 4; ++ni) { p[ni] = __expf(s[ni] - mnew); rs += p[ni]; }
                rs += __shfl_xor(rs, 1);
                rs += __shfl_xor(rs, 2);
                rs += __shfl_xor(rs, 4);
                rs += __shfl_xor(rs, 8);
                l_[t][r] = l_[t][r] * f + rs;
#pragma unroll
                for (int di = 0; di < 8; ++di) accO[t][di][r] *= f;
                int q = t * 16 + lk * 4 + r;
#pragma unroll
                for (int ni = 0; ni < 4; ++ni) {
                    int key = ni * 16 + lr;
                    Pl[wid][q * 64 + (((key >> 3) ^ (q & 7)) << 3) + (key & 7)] = f2bf(p[ni]);
                }
            }
        }

#pragma unroll
        for (int t = 0; t < 2; ++t) {
#pragma unroll
            for (int ksp = 0; ksp < 2; ++ksp) {
                int q = t * 16 + lr;
                int k0p = ksp * 32 + lk * 8;
                bf16x8 pa = *(const bf16x8*)&Pl[wid][q * 64 + (((k0p >> 3) ^ (q & 7)) << 3)];
                __builtin_amdgcn_s_setprio(1);
#pragma unroll
                for (int di = 0; di < 8; ++di) {
                    int row = di * 16 + lr;
                    int ch = (ksp * 4 + lk) ^ (row & 7);
                    bf16x8 vb = *(const bf16x8*)&Vl[cur][row * 64 + ch * 8];
                    accO[t][di] = __builtin_amdgcn_mfma_f32_16x16x32_bf16(
                        pa, vb, accO[t][di], 0, 0, 0);
                }
                __builtin_amdgcn_s_setprio(0);
            }
        }
        __syncthreads();
        cur ^= 1;
    }

    float inv[2][4];
#pragma unroll
    for (int t = 0; t < 2; ++t)
#pragma unroll
        for (int r = 0; r < 4; ++r) inv[t][r] = 1.f / l_[t][r];
#pragma unroll
    for (int t = 0; t < 2; ++t)
#pragma unroll
        for (int di = 0; di < 8; ++di) {
            int d = di * 16 + lr;
            if (d < DHEAD) {
#pragma unroll
                for (int r = 0; r < 4; ++r) {
                    int qg = q0 + t * 16 + lk * 4 + r;
                    ctxb[((size_t)b * NNODES + qg) * KP + h * DHEAD + d] =
                        f2bf(accO[t][di][r] * inv[t][r]);
                }
            }
        }
    if (h == 3) {
        int row = q0 + (lane & 31);
        int c0 = 500 + (lane >> 5) * 6;
#pragma unroll
        for (int j = 0; j < 6; ++j)
            ctxb[((size_t)b * NNODES + row) * KP + c0 + j] = 0;
    }
}

// ======================= layernorm bf16->bf16 (optional residual) ==============
__global__ __launch_bounds__(256) void ln_k(
    const ushort_t* __restrict__ x, const ushort_t* __restrict__ res,
    const float* __restrict__ g, const float* __restrict__ bta,
    ushort_t* __restrict__ outB)
{
    size_t row = blockIdx.x;
    const unsigned int* xr = (const unsigned int*)(x + row * KP);
    const unsigned int* rr = res ? (const unsigned int*)(res + row * KP) : nullptr;
    int t = threadIdx.x;           // thread t handles dims 2t, 2t+1
    int d0 = 2 * t;
    unsigned int xv = xr[t];
    float v0 = bf2f((unsigned short)(xv & 0xffff));
    float v1 = bf2f((unsigned short)(xv >> 16));
    if (rr) {
        unsigned int rv = rr[t];
        v0 += bf2f((unsigned short)(rv & 0xffff));
        v1 += bf2f((unsigned short)(rv >> 16));
    }
    if (d0 >= HSZ) v0 = 0.f;
    if (d0 + 1 >= HSZ) v1 = 0.f;
    float s = v0 + v1, s2 = v0 * v0 + v1 * v1;

    __shared__ float red[8];
    int wave = t >> 6, lane = t & 63;
    for (int o = 1; o < 64; o <<= 1) { s += __shfl_xor(s, o); s2 += __shfl_xor(s2, o); }
    if (lane == 0) { red[wave] = s; red[4 + wave] = s2; }
    __syncthreads();
    s  = red[0] + red[1] + red[2] + red[3];
    s2 = red[4] + red[5] + red[6] + red[7];
    float mean = s / HSZ;
    float var  = s2 / HSZ - mean * mean;
    float rstd = rsqrtf(var + 1e-5f);

    float o0 = 0.f, o1 = 0.f;
    if (d0 < HSZ)     o0 = (v0 - mean) * rstd * g[d0] + bta[d0];
    if (d0 + 1 < HSZ) o1 = (v1 - mean) * rstd * g[d0 + 1] + bta[d0 + 1];
    unsigned int pk = (unsigned int)f2bf(o0) | ((unsigned int)f2bf(o1) << 16);
    if (d0 >= HSZ) pk = 0;
    else if (d0 + 1 >= HSZ) pk = (unsigned int)f2bf(o0);
    ((unsigned int*)(outB + row * KP))[t] = pk;
}

// ======================= finalize (reads bf16 nodes): glob, node_emb, mask =====
__global__ __launch_bounds__(256) void finalize_k(
    const ushort_t* __restrict__ nodes, const int* __restrict__ entity_num,
    float* __restrict__ out)
{
    int b = blockIdx.x / NNODES;
    int n = blockIdx.x % NNODES;
    int e = entity_num[b];
    int size = e + RRELS;
    const ushort_t* src = nodes + ((size_t)b * NNODES + n) * KP;
    float* ne = out + (size_t)BB * HSZ + ((size_t)b * NNODES + n) * HSZ;
    bool valid = n < size;
    for (int d = threadIdx.x; d < HSZ; d += 256) ne[d] = valid ? bf2f(src[d]) : 0.f;
    if (n == e) {
        float* gl = out + (size_t)b * HSZ;
        for (int d = threadIdx.x; d < HSZ; d += 256) gl[d] = bf2f(src[d]);
    }
    if (threadIdx.x == 0) {
        out[(size_t)BB * HSZ + (size_t)BB * NNODES * HSZ + (size_t)b * NNODES + n] =
            (n <= size) ? 1.f : 0.f;
    }
}

// ======================= host =======================
extern "C" void kernel_launch(void* const* d_in, const int* in_sizes, int n_in,
                              void* d_out, int out_size, void* d_ws, size_t ws_size,
                              hipStream_t stream)
{
    const float* ent_vec    = (const float*)d_in[0];
    const int*   entity_num = (const int*)d_in[1];
    const int*   rels       = (const int*)d_in[2];
    const int*   adj        = (const int*)d_in[3];
    const float* rel_embed  = (const float*)d_in[4];
    const float* Wq = (const float*)d_in[5],  *bq = (const float*)d_in[6];
    const float* Wk = (const float*)d_in[7],  *bk = (const float*)d_in[8];
    const float* Wv = (const float*)d_in[9],  *bv = (const float*)d_in[10];
    const float* Wo = (const float*)d_in[11], *bo = (const float*)d_in[12];
    const float* W1 = (const float*)d_in[13], *b1 = (const float*)d_in[14];
    const float* W2 = (const float*)d_in[15], *b2 = (const float*)d_in[16];
    const float* ln1g = (const float*)d_in[17], *ln1b = (const float*)d_in[18];
    const float* ln2g = (const float*)d_in[19], *ln2b = (const float*)d_in[20];
    const float* pa = (const float*)d_in[21];

    const int M = BB * NNODES;               // 16384
    const size_t SP = (size_t)M * KP;        // 8,388,608 bf16

    ushort_t* Xb   = (ushort_t*)d_ws;        // [M][KP]  nodes bf16
    ushort_t* ctxb = Xb + SP;                // attention context
    ushort_t* tb   = ctxb + SP;              // t (ln1 out)
    ushort_t* ob   = tb + SP;                // o (O-proj out)
    ushort_t* fb   = ob + SP;                // f (W2 out)
    ushort_t* h1b  = fb + SP;                // [16384][2048] h1 (67.1MB)
    ushort_t* wqkvb = h1b + (size_t)M * HIDP;
    ushort_t* wob  = wqkvb + 3 * KP * KP;
    ushort_t* w1b  = wob + KP * KP;          // [HIDP][KP]
    ushort_t* w2b  = w1b + (size_t)HIDP * KP;// [KP][HIDP]

    // attn-phase aliases inside h1b (dead until W1)
    ushort_t* qh  = h1b;                     // [bh][512][128]
    ushort_t* kh  = h1b + SP;
    ushort_t* vTb = h1b + 2 * SP;            // [bh][128][512]

    unsigned int* abits = (unsigned int*)d_out;  // overwritten by finalize_k

    build_nodes_k<<<BB * NNODES, 256, 0, stream>>>(ent_vec, entity_num, rels, rel_embed, Xb);
    adj_bits_k<<<(BB * NNODES * NNODES) / 64 / 4, 256, 0, stream>>>(adj, abits);

    for (int l = 0; l < NLAYER; ++l) {
        const float* bq_l = bq + (size_t)l * HSZ;
        const float* bk_l = bk + (size_t)l * HSZ;
        const float* bv_l = bv + (size_t)l * HSZ;
        const float* bo_l = bo + (size_t)l * HSZ;
        const float* b1_l = b1 + (size_t)l * HID;
        const float* b2_l = b2 + (size_t)l * HSZ;
        const float* pa_l = pa + (size_t)l * HID;

        wcvt_t_k<<<768, 256, 0, stream>>>(
            Wq + (size_t)l * HSZ * HSZ, Wk + (size_t)l * HSZ * HSZ,
            Wv + (size_t)l * HSZ * HSZ, Wo + (size_t)l * HSZ * HSZ,
            W1 + (size_t)l * HSZ * HID, W2 + (size_t)l * HID * HSZ,
            wqkvb, wob, w1b, w2b);

        // fused QKV: writes qh, kh, and vT (transposed scatter) directly
        dim3 gQKV(1536 / 128, M / 128);  // (12, 128)
        gemm_mfma_k<<<gQKV, 256, 0, stream>>>(Xb, wqkvb, bq_l, bk_l, bv_l,
                                              qh, kh, vTb,
                                              M, 1536, KP, HSZ, nullptr, 1);

        attn_mfma_k<<<BB * NHEADS_ * 4, 256, 0, stream>>>(qh, kh, vTb, abits, ctxb);

        dim3 gO(KP / 128, M / 128);      // (4, 128)
        gemm_mfma_k<<<gO, 256, 0, stream>>>(ctxb, wob, bo_l, nullptr, nullptr,
                                            ob, nullptr, nullptr,
                                            M, KP, KP, HSZ, nullptr, 0);
        ln_k<<<M, 256, 0, stream>>>(ob, nullptr,
                                    ln1g + (size_t)l * HSZ, ln1b + (size_t)l * HSZ,
                                    tb);

        // FFN un-chunked: one W1 (M x 2048), one W2 (M x 512)
        dim3 g1(HIDP / 128, M / 128);    // (16, 128)
        gemm_mfma_k<<<g1, 256, 0, stream>>>(tb, w1b, b1_l, nullptr, nullptr,
                                            h1b, nullptr, nullptr,
                                            M, HIDP, KP, HID, pa_l, 0);
        dim3 g2(KP / 128, M / 128);      // (4, 128)
        gemm_mfma_k<<<g2, 256, 0, stream>>>(h1b, w2b, b2_l, nullptr, nullptr,
                                            fb, nullptr, nullptr,
                                            M, KP, HIDP, HSZ, nullptr, 0);

        ln_k<<<M, 256, 0, stream>>>(fb, tb,
                                    ln2g + (size_t)l * HSZ, ln2b + (size_t)l * HSZ,
                                    Xb);
    }

    finalize_k<<<BB * NNODES, 256, 0, stream>>>(Xb, entity_num, (float*)d_out);
}

// Round 13
// 529.008 us; speedup vs baseline: 1.4482x; 1.0032x over previous
//
#include <hip/hip_runtime.h>

#define BB 32
#define MEE 384
#define RRELS 128
#define NNODES 512
#define HSZ 500
#define DHEAD 125
#define NHEADS_ 4
#define HID 2000
#define NLAYER 2

#define KP 512      // padded HSZ
#define HIDP 2048   // padded HID

typedef unsigned short ushort_t;
typedef __attribute__((ext_vector_type(8))) short bf16x8;
typedef __attribute__((ext_vector_type(4))) float f32x4;
typedef __attribute__((ext_vector_type(4))) short s16x4;

static __device__ __forceinline__ unsigned short f2bf(float x) {
    unsigned u = __float_as_uint(x);
    u = u + 0x7fff + ((u >> 16) & 1);   // round-to-nearest-even
    return (unsigned short)(u >> 16);
}
static __device__ __forceinline__ float bf2f(unsigned short b) {
    return __uint_as_float((unsigned)b << 16);
}

static __device__ __forceinline__ void gload_lds16(const ushort_t* g, ushort_t* l) {
    __builtin_amdgcn_global_load_lds(
        (const __attribute__((address_space(1))) void*)g,
        (__attribute__((address_space(3))) void*)l, 16, 0, 0);
}

// ======================= build nodes (bf16-padded) =======================
__global__ __launch_bounds__(256) void build_nodes_k(
    const float* __restrict__ ent_vec, const int* __restrict__ entity_num,
    const int* __restrict__ rels, const float* __restrict__ rel_embed,
    ushort_t* __restrict__ xb)
{
    int b = blockIdx.x / NNODES;
    int n = blockIdx.x % NNODES;
    int e = entity_num[b];
    const float* src = nullptr;
    if (n < e)               src = ent_vec + ((size_t)b * MEE + n) * HSZ;
    else if (n < e + RRELS)  src = rel_embed + (size_t)rels[b * RRELS + (n - e)] * HSZ;
    ushort_t* xd = xb + ((size_t)b * NNODES + n) * KP;
    for (int d = threadIdx.x; d < KP; d += 256)
        xd[d] = (src && d < HSZ) ? f2bf(src[d]) : 0;
}

// ======================= adjacency -> bitmask =======================
__global__ __launch_bounds__(256) void adj_bits_k(
    const int* __restrict__ adj, unsigned int* __restrict__ bits)
{
    int gw = (blockIdx.x * 256 + threadIdx.x) >> 6;
    int lane = threadIdx.x & 63;
    int v = adj[(size_t)gw * 64 + lane];
    unsigned long long mk = __ballot(v != 0);
    if (lane == 0)  bits[gw * 2]     = (unsigned int)mk;
    if (lane == 32) bits[gw * 2 + 1] = (unsigned int)(mk >> 32);
}

// ======================= all-weights convert: LDS-tiled transpose ==============
// 768 blocks: [0,192) wqkv, [192,256) wo, [256,512) w1, [512,768) w2
__global__ __launch_bounds__(256) void wcvt_t_k(
    const float* __restrict__ pWq, const float* __restrict__ pWk,
    const float* __restrict__ pWv, const float* __restrict__ pWo,
    const float* __restrict__ pW1, const float* __restrict__ pW2,
    ushort_t* __restrict__ wqkv, ushort_t* __restrict__ wo,
    ushort_t* __restrict__ w1, ushort_t* __restrict__ w2)
{
    __shared__ float T[64][65];
    int blk = blockIdx.x;
    const float* W; ushort_t* out; int Kr, Nr, Kpp, tt;
    if (blk < 192)      { int s = blk >> 6; W = s == 0 ? pWq : (s == 1 ? pWk : pWv);
                          out = wqkv + s * 262144; Kr = 500; Nr = 500; Kpp = 512; tt = blk & 63; }
    else if (blk < 256) { W = pWo; out = wo;  Kr = 500;  Nr = 500;  Kpp = 512;  tt = blk - 192; }
    else if (blk < 512) { W = pW1; out = w1;  Kr = 500;  Nr = 2000; Kpp = 512;  tt = blk - 256; }
    else                { W = pW2; out = w2;  Kr = 2000; Nr = 500;  Kpp = 2048; tt = blk - 512; }
    int ntk = Kpp >> 6;
    int tk = tt % ntk, tn = tt / ntk;
    int tid = threadIdx.x;
#pragma unroll
    for (int p = 0; p < 4; ++p) {
        int kl = p * 16 + (tid >> 4);
        int k  = tk * 64 + kl;
        int nl = (tid & 15) * 4;
        int n  = tn * 64 + nl;
        float4 v = make_float4(0.f, 0.f, 0.f, 0.f);
        if (k < Kr) {
            if (n + 3 < Nr) v = *(const float4*)&W[(size_t)k * Nr + n];
            else {
                if (n     < Nr) v.x = W[(size_t)k * Nr + n];
                if (n + 1 < Nr) v.y = W[(size_t)k * Nr + n + 1];
                if (n + 2 < Nr) v.z = W[(size_t)k * Nr + n + 2];
                if (n + 3 < Nr) v.w = W[(size_t)k * Nr + n + 3];
            }
        }
        T[kl][nl] = v.x; T[kl][nl + 1] = v.y; T[kl][nl + 2] = v.z; T[kl][nl + 3] = v.w;
    }
    __syncthreads();
#pragma unroll
    for (int p = 0; p < 2; ++p) {
        int nl  = p * 32 + (tid >> 3);
        int kl8 = (tid & 7) * 8;
        bf16x8 o;
#pragma unroll
        for (int j = 0; j < 8; ++j) o[j] = (short)f2bf(T[kl8 + j][nl]);
        *(bf16x8*)&out[(size_t)(tn * 64 + nl) * Kpp + tk * 64 + kl8] = o;
    }
}

// ======================= bf16 MFMA GEMM (128x128, BK=32, 2-phase dbuf) ==========
__global__ __launch_bounds__(256, 2) void gemm_mfma_k(
    const ushort_t* __restrict__ A, const ushort_t* __restrict__ Bt,
    const float* __restrict__ bias0, const float* __restrict__ bias1,
    const float* __restrict__ bias2,
    ushort_t* __restrict__ outB, ushort_t* __restrict__ outK,
    ushort_t* __restrict__ outV,
    int M, int Np, int Kp, int Nreal,
    const float* __restrict__ prelu, int mode)
{
    __shared__ ushort_t Al[2][128 * 32];
    __shared__ ushort_t Bl[2][128 * 32];

    const int nwg = gridDim.x * gridDim.y;
    const int bid = blockIdx.y * gridDim.x + blockIdx.x;
    const int swz = (bid & 7) * (nwg >> 3) + (bid >> 3);
    const int bm = (swz / gridDim.x) * 128;
    const int bn = (swz % gridDim.x) * 128;

    const int tid = threadIdx.x;
    const int wid = tid >> 6, lane = tid & 63;
    const int wr = wid >> 1, wc = wid & 1;
    const int lr = lane & 15, lk = lane >> 4;

    f32x4 acc[4][4];
#pragma unroll
    for (int i = 0; i < 4; ++i)
#pragma unroll
        for (int j = 0; j < 4; ++j)
#pragma unroll
            for (int r = 0; r < 4; ++r) acc[i][j][r] = 0.f;

    const int srow = tid >> 2;
    const int skseg = (tid & 3) * 8;
    const ushort_t* Ag0 = A + (size_t)(bm + srow) * Kp + skseg;
    const ushort_t* Ag1 = A + (size_t)(bm + 64 + srow) * Kp + skseg;
    const ushort_t* Bg0 = Bt + (size_t)(bn + srow) * Kp + skseg;
    const ushort_t* Bg1 = Bt + (size_t)(bn + 64 + srow) * Kp + skseg;

    auto stage = [&](int bi, int k0) {
        gload_lds16(Ag0 + k0, &Al[bi][wid * 512]);
        gload_lds16(Ag1 + k0, &Al[bi][2048 + wid * 512]);
        gload_lds16(Bg0 + k0, &Bl[bi][wid * 512]);
        gload_lds16(Bg1 + k0, &Bl[bi][2048 + wid * 512]);
    };

    stage(0, 0);
    __syncthreads();
    int cur = 0;

    for (int k0 = 0; k0 < Kp; k0 += 32) {
        if (k0 + 32 < Kp) stage(cur ^ 1, k0 + 32);   // prefetch under compute

        bf16x8 af[4], bfr[4];
#pragma unroll
        for (int mi = 0; mi < 4; ++mi)
            af[mi] = *(const bf16x8*)&Al[cur][(wr * 64 + mi * 16 + lr) * 32 + lk * 8];
#pragma unroll
        for (int ni = 0; ni < 4; ++ni)
            bfr[ni] = *(const bf16x8*)&Bl[cur][(wc * 64 + ni * 16 + lr) * 32 + lk * 8];
        __builtin_amdgcn_s_setprio(1);
#pragma unroll
        for (int mi = 0; mi < 4; ++mi)
#pragma unroll
            for (int ni = 0; ni < 4; ++ni)
                acc[mi][ni] = __builtin_amdgcn_mfma_f32_16x16x32_bf16(
                    af[mi], bfr[ni], acc[mi][ni], 0, 0, 0);
        __builtin_amdgcn_s_setprio(0);

        __syncthreads();
        cur ^= 1;
    }

    if (mode == 1) {
#pragma unroll
        for (int ni = 0; ni < 4; ++ni) {
            int col = bn + wc * 64 + ni * 16 + lr;
            int reg = col >> 9, c = col & 511;
            bool cok = c < 500;
            int hh, dh;
            if (cok) { hh = c / 125; dh = c - hh * 125; }
            else     { hh = (c - 500) / 3; dh = 125 + (c - 500) % 3; }
            const float* bp = reg == 0 ? bias0 : (reg == 1 ? bias1 : bias2);
            float bv = cok ? bp[c] : 0.f;
#pragma unroll
            for (int mi = 0; mi < 4; ++mi) {
                int row0 = bm + wr * 64 + mi * 16 + lk * 4;
                int b_ = row0 >> 9, n0 = row0 & 511;
                size_t bh = (size_t)b_ * 4 + hh;
                if (reg == 2) {
                    s16x4 pk;
#pragma unroll
                    for (int r = 0; r < 4; ++r) {
                        float val = acc[mi][ni][r] + bv;
                        pk[r] = cok ? (short)f2bf(val) : (short)0;
                    }
                    *(s16x4*)&outV[(bh * 128 + dh) * 512 + n0] = pk;
                } else {
                    ushort_t* dst = reg == 0 ? outB : outK;
#pragma unroll
                    for (int r = 0; r < 4; ++r) {
                        float val = acc[mi][ni][r] + bv;
                        dst[(bh * 512 + n0 + r) * 128 + dh] = cok ? f2bf(val) : 0;
                    }
                }
            }
        }
    } else {
#pragma unroll
        for (int ni = 0; ni < 4; ++ni) {
            int col = bn + wc * 64 + ni * 16 + lr;
            bool cok = col < Nreal;
            float bv = cok ? bias0[col] : 0.f;
            float pv = (prelu && cok) ? prelu[col] : 0.f;
#pragma unroll
            for (int mi = 0; mi < 4; ++mi) {
                int row0 = bm + wr * 64 + mi * 16 + lk * 4;
#pragma unroll
                for (int r = 0; r < 4; ++r) {
                    int row = row0 + r;
                    float val = acc[mi][ni][r] + bv;
                    if (prelu) val = val > 0.f ? val : pv * val;
                    outB[(size_t)row * Np + col] = cok ? f2bf(val) : 0;
                }
            }
        }
    }
}

// ======================= MFMA flash attention v3 (defer-max + exp2 domain) =====
#define KTT 64
__global__ __launch_bounds__(256, 2) void attn_mfma_k(
    const ushort_t* __restrict__ qh, const ushort_t* __restrict__ kh,
    const ushort_t* __restrict__ vT, const unsigned int* __restrict__ abits,
    ushort_t* __restrict__ ctxb)
{
    __shared__ ushort_t Kl[2][KTT * 128];    // 2 x 16KB
    __shared__ ushort_t Vl[2][128 * KTT];    // 2 x 16KB
    __shared__ ushort_t Pl[4][32 * KTT];     // 16KB

    const int bid = blockIdx.x;
    const int wg = (bid & 7) * 64 + (bid >> 3);   // 512 wgs: chunked XCD swizzle
    const int qt2 = wg & 3, bh = wg >> 2;
    const int b = bh >> 2, h = bh & 3;
    const int tid = threadIdx.x, wid = tid >> 6, lane = tid & 63;
    const int lr = lane & 15, lk = lane >> 4;
    const int q0 = qt2 * 128 + wid * 32;          // wave's 32 q rows
    // scale * log2(e): softmax carried in exp2 domain (bare v_exp_f32)
    const float scale2 = 0.08944271909999159f * 1.44269504088896f;

    bf16x8 qa[2][4];
#pragma unroll
    for (int t = 0; t < 2; ++t) {
        const ushort_t* qbase = qh + ((size_t)bh * 512 + q0 + t * 16 + lr) * 128;
#pragma unroll
        for (int ks = 0; ks < 4; ++ks)
            qa[t][ks] = *(const bf16x8*)&qbase[ks * 32 + lk * 8];
    }

    f32x4 accO[2][8];
#pragma unroll
    for (int t = 0; t < 2; ++t)
#pragma unroll
        for (int i = 0; i < 8; ++i)
#pragma unroll
            for (int r = 0; r < 4; ++r) accO[t][i][r] = 0.f;
    float m_[2][4], l_[2][4];
#pragma unroll
    for (int t = 0; t < 2; ++t)
#pragma unroll
        for (int r = 0; r < 4; ++r) { m_[t][r] = -3e38f; l_[t][r] = 0.f; }

    const unsigned int* ab = abits + ((size_t)b * NNODES + q0) * 16;

    auto stage = [&](int bi, int kt) {
#pragma unroll
        for (int i = 0; i < 4; ++i) {
            int linear = (wid * 4 + i) * 64 + lane;
            int row = linear >> 4, cc = linear & 15;
            int cs = cc ^ (row & 7);
            gload_lds16(kh + ((size_t)bh * 512 + kt * 64 + row) * 128 + cs * 8,
                        &Kl[bi][(wid * 4 + i) * 512]);
        }
#pragma unroll
        for (int i = 0; i < 4; ++i) {
            int linear = (wid * 4 + i) * 64 + lane;
            int row = linear >> 3, cc = linear & 7;
            int cs = cc ^ (row & 7);
            gload_lds16(vT + ((size_t)bh * 128 + row) * 512 + kt * 64 + cs * 8,
                        &Vl[bi][(wid * 4 + i) * 512]);
        }
    };

    stage(0, 0);
    __syncthreads();
    int cur = 0;

    for (int kt = 0; kt < NNODES / KTT; ++kt) {
        if (kt < NNODES / KTT - 1) stage(cur ^ 1, kt + 1);  // prefetch under compute

        unsigned int mw[2][4][2];
#pragma unroll
        for (int t = 0; t < 2; ++t)
#pragma unroll
            for (int r = 0; r < 4; ++r) {
                int qrow = t * 16 + lk * 4 + r;
                mw[t][r][0] = ab[qrow * 16 + kt * 2];
                mw[t][r][1] = ab[qrow * 16 + kt * 2 + 1];
            }

#pragma unroll
        for (int t = 0; t < 2; ++t) {
            f32x4 accS[4];
#pragma unroll
            for (int ni = 0; ni < 4; ++ni)
#pragma unroll
                for (int r = 0; r < 4; ++r) accS[ni][r] = 0.f;
            __builtin_amdgcn_s_setprio(1);
#pragma unroll
            for (int ks = 0; ks < 4; ++ks) {
#pragma unroll
                for (int ni = 0; ni < 4; ++ni) {
                    int row = ni * 16 + lr;
                    int ch = (ks * 4 + lk) ^ (row & 7);
                    bf16x8 kb = *(const bf16x8*)&Kl[cur][row * 128 + ch * 8];
                    accS[ni] = __builtin_amdgcn_mfma_f32_16x16x32_bf16(
                        qa[t][ks], kb, accS[ni], 0, 0, 0);
                }
            }
            __builtin_amdgcn_s_setprio(0);

            // ---- masked online softmax (exp2 domain, wave-uniform defer-max) ----
            float s_all[4][4], mnew[4];
#pragma unroll
            for (int r = 0; r < 4; ++r) {
                float rowmax = -3e38f;
#pragma unroll
                for (int ni = 0; ni < 4; ++ni) {
                    unsigned int word = mw[t][r][ni >> 1];
                    int bit = (ni & 1) * 16 + lr;
                    bool on = (word >> bit) & 1u;
                    float sv = on ? accS[ni][r] * scale2 : -1e9f;
                    s_all[r][ni] = sv;
                    rowmax = fmaxf(rowmax, sv);
                }
                rowmax = fmaxf(rowmax, __shfl_xor(rowmax, 1));
                rowmax = fmaxf(rowmax, __shfl_xor(rowmax, 2));
                rowmax = fmaxf(rowmax, __shfl_xor(rowmax, 4));
                rowmax = fmaxf(rowmax, __shfl_xor(rowmax, 8));
                mnew[r] = fmaxf(m_[t][r], rowmax);
            }
            // T13 defer-max: skip rescale unless some row grew by > 8 (P <= 2^8)
            bool need = false;
#pragma unroll
            for (int r = 0; r < 4; ++r) need = need || (mnew[r] - m_[t][r] > 8.f);
            if (__any(need)) {
#pragma unroll
                for (int r = 0; r < 4; ++r) {
                    float f = exp2f(m_[t][r] - mnew[r]);
                    m_[t][r] = mnew[r];
                    l_[t][r] *= f;
#pragma unroll
                    for (int di = 0; di < 8; ++di) accO[t][di][r] *= f;
                }
            }
#pragma unroll
            for (int r = 0; r < 4; ++r) {
                float p[4], rs = 0.f;
#pragma unroll
                for (int ni = 0; ni < 4; ++ni) {
                    p[ni] = exp2f(s_all[r][ni] - m_[t][r]);
                    rs += p[ni];
                }
                rs += __shfl_xor(rs, 1);
                rs += __shfl_xor(rs, 2);
                rs += __shfl_xor(rs, 4);
                rs += __shfl_xor(rs, 8);
                l_[t][r] += rs;
                int q = t * 16 + lk * 4 + r;
#pragma unroll
                for (int ni = 0; ni < 4; ++ni) {
                    int key = ni * 16 + lr;
                    Pl[wid][q * 64 + (((key >> 3) ^ (q & 7)) << 3) + (key & 7)] = f2bf(p[ni]);
                }
            }
        }

#pragma unroll
        for (int t = 0; t < 2; ++t) {
#pragma unroll
            for (int ksp = 0; ksp < 2; ++ksp) {
                int q = t * 16 + lr;
                int k0p = ksp * 32 + lk * 8;
                bf16x8 pa = *(const bf16x8*)&Pl[wid][q * 64 + (((k0p >> 3) ^ (q & 7)) << 3)];
                __builtin_amdgcn_s_setprio(1);
#pragma unroll
                for (int di = 0; di < 8; ++di) {
                    int row = di * 16 + lr;
                    int ch = (ksp * 4 + lk) ^ (row & 7);
                    bf16x8 vb = *(const bf16x8*)&Vl[cur][row * 64 + ch * 8];
                    accO[t][di] = __builtin_amdgcn_mfma_f32_16x16x32_bf16(
                        pa, vb, accO[t][di], 0, 0, 0);
                }
                __builtin_amdgcn_s_setprio(0);
            }
        }
        __syncthreads();
        cur ^= 1;
    }

    float inv[2][4];
#pragma unroll
    for (int t = 0; t < 2; ++t)
#pragma unroll
        for (int r = 0; r < 4; ++r) inv[t][r] = 1.f / l_[t][r];
#pragma unroll
    for (int t = 0; t < 2; ++t)
#pragma unroll
        for (int di = 0; di < 8; ++di) {
            int d = di * 16 + lr;
            if (d < DHEAD) {
#pragma unroll
                for (int r = 0; r < 4; ++r) {
                    int qg = q0 + t * 16 + lk * 4 + r;
                    ctxb[((size_t)b * NNODES + qg) * KP + h * DHEAD + d] =
                        f2bf(accO[t][di][r] * inv[t][r]);
                }
            }
        }
    if (h == 3) {
        int row = q0 + (lane & 31);
        int c0 = 500 + (lane >> 5) * 6;
#pragma unroll
        for (int j = 0; j < 6; ++j)
            ctxb[((size_t)b * NNODES + row) * KP + c0 + j] = 0;
    }
}

// ======================= layernorm bf16->bf16 (optional residual / final out) ==
// final!=0: instead of writing outB, write f32 outputs directly:
//   glob [BB][HSZ], node_emb [BB][NNODES][HSZ] (masked), out_mask [BB][NNODES]
__global__ __launch_bounds__(256) void ln_k(
    const ushort_t* __restrict__ x, const ushort_t* __restrict__ res,
    const float* __restrict__ g, const float* __restrict__ bta,
    ushort_t* __restrict__ outB,
    const int* __restrict__ entity_num, float* __restrict__ out, int final_)
{
    size_t row = blockIdx.x;
    const unsigned int* xr = (const unsigned int*)(x + row * KP);
    const unsigned int* rr = res ? (const unsigned int*)(res + row * KP) : nullptr;
    int t = threadIdx.x;           // thread t handles dims 2t, 2t+1
    int d0 = 2 * t;
    unsigned int xv = xr[t];
    float v0 = bf2f((unsigned short)(xv & 0xffff));
    float v1 = bf2f((unsigned short)(xv >> 16));
    if (rr) {
        unsigned int rv = rr[t];
        v0 += bf2f((unsigned short)(rv & 0xffff));
        v1 += bf2f((unsigned short)(rv >> 16));
    }
    if (d0 >= HSZ) v0 = 0.f;
    if (d0 + 1 >= HSZ) v1 = 0.f;
    float s = v0 + v1, s2 = v0 * v0 + v1 * v1;

    __shared__ float red[8];
    int wave = t >> 6, lane = t & 63;
    for (int o = 1; o < 64; o <<= 1) { s += __shfl_xor(s, o); s2 += __shfl_xor(s2, o); }
    if (lane == 0) { red[wave] = s; red[4 + wave] = s2; }
    __syncthreads();
    s  = red[0] + red[1] + red[2] + red[3];
    s2 = red[4] + red[5] + red[6] + red[7];
    float mean = s / HSZ;
    float var  = s2 / HSZ - mean * mean;
    float rstd = rsqrtf(var + 1e-5f);

    float o0 = 0.f, o1 = 0.f;
    if (d0 < HSZ)     o0 = (v0 - mean) * rstd * g[d0] + bta[d0];
    if (d0 + 1 < HSZ) o1 = (v1 - mean) * rstd * g[d0 + 1] + bta[d0 + 1];

    if (!final_) {
        unsigned int pk = (unsigned int)f2bf(o0) | ((unsigned int)f2bf(o1) << 16);
        if (d0 >= HSZ) pk = 0;
        else if (d0 + 1 >= HSZ) pk = (unsigned int)f2bf(o0);
        ((unsigned int*)(outB + row * KP))[t] = pk;
    } else {
        int b = (int)(row >> 9), n = (int)(row & 511);
        int e = entity_num[b];
        int size = e + RRELS;
        bool valid = n < size;
        float* ne = out + (size_t)BB * HSZ + row * HSZ;
        if (d0 < HSZ)     ne[d0]     = valid ? o0 : 0.f;
        if (d0 + 1 < HSZ) ne[d0 + 1] = valid ? o1 : 0.f;
        if (n == e) {
            float* gl = out + (size_t)b * HSZ;
            if (d0 < HSZ)     gl[d0]     = o0;
            if (d0 + 1 < HSZ) gl[d0 + 1] = o1;
        }
        if (t == 0)
            out[(size_t)BB * HSZ + (size_t)BB * NNODES * HSZ + row] =
                (n <= size) ? 1.f : 0.f;
    }
}

// ======================= host =======================
extern "C" void kernel_launch(void* const* d_in, const int* in_sizes, int n_in,
                              void* d_out, int out_size, void* d_ws, size_t ws_size,
                              hipStream_t stream)
{
    const float* ent_vec    = (const float*)d_in[0];
    const int*   entity_num = (const int*)d_in[1];
    const int*   rels       = (const int*)d_in[2];
    const int*   adj        = (const int*)d_in[3];
    const float* rel_embed  = (const float*)d_in[4];
    const float* Wq = (const float*)d_in[5],  *bq = (const float*)d_in[6];
    const float* Wk = (const float*)d_in[7],  *bk = (const float*)d_in[8];
    const float* Wv = (const float*)d_in[9],  *bv = (const float*)d_in[10];
    const float* Wo = (const float*)d_in[11], *bo = (const float*)d_in[12];
    const float* W1 = (const float*)d_in[13], *b1 = (const float*)d_in[14];
    const float* W2 = (const float*)d_in[15], *b2 = (const float*)d_in[16];
    const float* ln1g = (const float*)d_in[17], *ln1b = (const float*)d_in[18];
    const float* ln2g = (const float*)d_in[19], *ln2b = (const float*)d_in[20];
    const float* pa = (const float*)d_in[21];

    const int M = BB * NNODES;               // 16384
    const size_t SP = (size_t)M * KP;        // 8,388,608 bf16

    ushort_t* Xb   = (ushort_t*)d_ws;        // [M][KP]  nodes bf16
    ushort_t* ctxb = Xb + SP;                // attention context
    ushort_t* tb   = ctxb + SP;              // t (ln1 out)
    ushort_t* ob   = tb + SP;                // o (O-proj out)
    ushort_t* fb   = ob + SP;                // f (W2 out)
    ushort_t* h1b  = fb + SP;                // [16384][2048] h1 (67.1MB)
    ushort_t* wqkvb = h1b + (size_t)M * HIDP;
    ushort_t* wob  = wqkvb + 3 * KP * KP;
    ushort_t* w1b  = wob + KP * KP;          // [HIDP][KP]
    ushort_t* w2b  = w1b + (size_t)HIDP * KP;// [KP][HIDP]

    // attn-phase aliases inside h1b (dead until W1)
    ushort_t* qh  = h1b;                     // [bh][512][128]
    ushort_t* kh  = h1b + SP;
    ushort_t* vTb = h1b + 2 * SP;            // [bh][128][512]

    unsigned int* abits = (unsigned int*)d_out;  // overwritten by final ln_k

    build_nodes_k<<<BB * NNODES, 256, 0, stream>>>(ent_vec, entity_num, rels, rel_embed, Xb);
    adj_bits_k<<<(BB * NNODES * NNODES) / 64 / 4, 256, 0, stream>>>(adj, abits);

    for (int l = 0; l < NLAYER; ++l) {
        const float* bq_l = bq + (size_t)l * HSZ;
        const float* bk_l = bk + (size_t)l * HSZ;
        const float* bv_l = bv + (size_t)l * HSZ;
        const float* bo_l = bo + (size_t)l * HSZ;
        const float* b1_l = b1 + (size_t)l * HID;
        const float* b2_l = b2 + (size_t)l * HSZ;
        const float* pa_l = pa + (size_t)l * HID;

        wcvt_t_k<<<768, 256, 0, stream>>>(
            Wq + (size_t)l * HSZ * HSZ, Wk + (size_t)l * HSZ * HSZ,
            Wv + (size_t)l * HSZ * HSZ, Wo + (size_t)l * HSZ * HSZ,
            W1 + (size_t)l * HSZ * HID, W2 + (size_t)l * HID * HSZ,
            wqkvb, wob, w1b, w2b);

        // fused QKV: writes qh, kh, and vT (transposed scatter) directly
        dim3 gQKV(1536 / 128, M / 128);  // (12, 128)
        gemm_mfma_k<<<gQKV, 256, 0, stream>>>(Xb, wqkvb, bq_l, bk_l, bv_l,
                                              qh, kh, vTb,
                                              M, 1536, KP, HSZ, nullptr, 1);

        attn_mfma_k<<<BB * NHEADS_ * 4, 256, 0, stream>>>(qh, kh, vTb, abits, ctxb);

        dim3 gO(KP / 128, M / 128);      // (4, 128)
        gemm_mfma_k<<<gO, 256, 0, stream>>>(ctxb, wob, bo_l, nullptr, nullptr,
                                            ob, nullptr, nullptr,
                                            M, KP, KP, HSZ, nullptr, 0);
        ln_k<<<M, 256, 0, stream>>>(ob, nullptr,
                                    ln1g + (size_t)l * HSZ, ln1b + (size_t)l * HSZ,
                                    tb, nullptr, nullptr, 0);

        // FFN un-chunked: one W1 (M x 2048), one W2 (M x 512)
        dim3 g1(HIDP / 128, M / 128);    // (16, 128)
        gemm_mfma_k<<<g1, 256, 0, stream>>>(tb, w1b, b1_l, nullptr, nullptr,
                                            h1b, nullptr, nullptr,
                                            M, HIDP, KP, HID, pa_l, 0);
        dim3 g2(KP / 128, M / 128);      // (4, 128)
        gemm_mfma_k<<<g2, 256, 0, stream>>>(h1b, w2b, b2_l, nullptr, nullptr,
                                            fb, nullptr, nullptr,
                                            M, KP, HIDP, HSZ, nullptr, 0);

        int fin = (l == NLAYER - 1) ? 1 : 0;
        ln_k<<<M, 256, 0, stream>>>(fb, tb,
                                    ln2g + (size_t)l * HSZ, ln2b + (size_t)l * HSZ,
                                    Xb, entity_num, (float*)d_out, fin);
    }
}

// Round 14
// 524.427 us; speedup vs baseline: 1.4609x; 1.0087x over previous
//
#include <hip/hip_runtime.h>

#define BB 32
#define MEE 384
#define RRELS 128
#define NNODES 512
#define HSZ 500
#define DHEAD 125
#define NHEADS_ 4
#define HID 2000
#define NLAYER 2

#define KP 512      // padded HSZ
#define HIDP 2048   // padded HID

typedef unsigned short ushort_t;
typedef __attribute__((ext_vector_type(8))) short bf16x8;
typedef __attribute__((ext_vector_type(4))) float f32x4;
typedef __attribute__((ext_vector_type(4))) short s16x4;

static __device__ __forceinline__ unsigned short f2bf(float x) {
    unsigned u = __float_as_uint(x);
    u = u + 0x7fff + ((u >> 16) & 1);   // round-to-nearest-even
    return (unsigned short)(u >> 16);
}
static __device__ __forceinline__ float bf2f(unsigned short b) {
    return __uint_as_float((unsigned)b << 16);
}

static __device__ __forceinline__ void gload_lds16(const ushort_t* g, ushort_t* l) {
    __builtin_amdgcn_global_load_lds(
        (const __attribute__((address_space(1))) void*)g,
        (__attribute__((address_space(3))) void*)l, 16, 0, 0);
}

// ======================= build nodes (bf16-padded) =======================
__global__ __launch_bounds__(256) void build_nodes_k(
    const float* __restrict__ ent_vec, const int* __restrict__ entity_num,
    const int* __restrict__ rels, const float* __restrict__ rel_embed,
    ushort_t* __restrict__ xb)
{
    int b = blockIdx.x / NNODES;
    int n = blockIdx.x % NNODES;
    int e = entity_num[b];
    const float* src = nullptr;
    if (n < e)               src = ent_vec + ((size_t)b * MEE + n) * HSZ;
    else if (n < e + RRELS)  src = rel_embed + (size_t)rels[b * RRELS + (n - e)] * HSZ;
    ushort_t* xd = xb + ((size_t)b * NNODES + n) * KP;
    for (int d = threadIdx.x; d < KP; d += 256)
        xd[d] = (src && d < HSZ) ? f2bf(src[d]) : 0;
}

// ======================= adjacency -> bitmask =======================
__global__ __launch_bounds__(256) void adj_bits_k(
    const int* __restrict__ adj, unsigned int* __restrict__ bits)
{
    int gw = (blockIdx.x * 256 + threadIdx.x) >> 6;
    int lane = threadIdx.x & 63;
    int v = adj[(size_t)gw * 64 + lane];
    unsigned long long mk = __ballot(v != 0);
    if (lane == 0)  bits[gw * 2]     = (unsigned int)mk;
    if (lane == 32) bits[gw * 2 + 1] = (unsigned int)(mk >> 32);
}

// ======================= all-weights convert, BOTH layers, one launch ==========
// 1536 blocks; per layer: [0,192) wqkv, [192,256) wo, [256,512) w1, [512,768) w2
__global__ __launch_bounds__(256) void wcvt_t_k(
    const float* __restrict__ pWq, const float* __restrict__ pWk,
    const float* __restrict__ pWv, const float* __restrict__ pWo,
    const float* __restrict__ pW1, const float* __restrict__ pW2,
    ushort_t* __restrict__ wqkv, ushort_t* __restrict__ wo,
    ushort_t* __restrict__ w1, ushort_t* __restrict__ w2)
{
    __shared__ float T[64][65];
    int blk0 = blockIdx.x;
    int layer = blk0 >> 9 >= 1 && blk0 >= 768 ? 1 : 0;   // blk0/768
    layer = blk0 / 768;
    int blk = blk0 - layer * 768;
    const float* W; ushort_t* out; int Kr, Nr, Kpp, tt;
    if (blk < 192)      { int s = blk >> 6;
                          W = (s == 0 ? pWq : (s == 1 ? pWk : pWv)) + (size_t)layer * HSZ * HSZ;
                          out = wqkv + (size_t)layer * 786432 + s * 262144;
                          Kr = 500; Nr = 500; Kpp = 512; tt = blk & 63; }
    else if (blk < 256) { W = pWo + (size_t)layer * HSZ * HSZ;
                          out = wo + (size_t)layer * 262144;
                          Kr = 500;  Nr = 500;  Kpp = 512;  tt = blk - 192; }
    else if (blk < 512) { W = pW1 + (size_t)layer * HSZ * HID;
                          out = w1 + (size_t)layer * 1048576;
                          Kr = 500;  Nr = 2000; Kpp = 512;  tt = blk - 256; }
    else                { W = pW2 + (size_t)layer * HID * HSZ;
                          out = w2 + (size_t)layer * 1048576;
                          Kr = 2000; Nr = 500;  Kpp = 2048; tt = blk - 512; }
    int ntk = Kpp >> 6;
    int tk = tt % ntk, tn = tt / ntk;
    int tid = threadIdx.x;
#pragma unroll
    for (int p = 0; p < 4; ++p) {
        int kl = p * 16 + (tid >> 4);
        int k  = tk * 64 + kl;
        int nl = (tid & 15) * 4;
        int n  = tn * 64 + nl;
        float4 v = make_float4(0.f, 0.f, 0.f, 0.f);
        if (k < Kr) {
            if (n + 3 < Nr) v = *(const float4*)&W[(size_t)k * Nr + n];
            else {
                if (n     < Nr) v.x = W[(size_t)k * Nr + n];
                if (n + 1 < Nr) v.y = W[(size_t)k * Nr + n + 1];
                if (n + 2 < Nr) v.z = W[(size_t)k * Nr + n + 2];
                if (n + 3 < Nr) v.w = W[(size_t)k * Nr + n + 3];
            }
        }
        T[kl][nl] = v.x; T[kl][nl + 1] = v.y; T[kl][nl + 2] = v.z; T[kl][nl + 3] = v.w;
    }
    __syncthreads();
#pragma unroll
    for (int p = 0; p < 2; ++p) {
        int nl  = p * 32 + (tid >> 3);
        int kl8 = (tid & 7) * 8;
        bf16x8 o;
#pragma unroll
        for (int j = 0; j < 8; ++j) o[j] = (short)f2bf(T[kl8 + j][nl]);
        *(bf16x8*)&out[(size_t)(tn * 64 + nl) * Kpp + tk * 64 + kl8] = o;
    }
}

// ======================= bf16 MFMA GEMM (128x128, BK=32, 3-deep counted-vmcnt) ==
// A: [M, Kp] bf16. Bt: [Np, Kp] bf16 (W^T).
// mode 0: outB = bf16 [M, Np], zero-padded cols, optional PReLU (direct stores)
// mode 1: fused QKV, Np=1536: region 0->outB(qh), 1->outK(kh),
//         2->outV = V^T [bh][128][512] (scatter, s16x4)
__global__ __launch_bounds__(256, 3) void gemm_mfma_k(
    const ushort_t* __restrict__ A, const ushort_t* __restrict__ Bt,
    const float* __restrict__ bias0, const float* __restrict__ bias1,
    const float* __restrict__ bias2,
    ushort_t* __restrict__ outB, ushort_t* __restrict__ outK,
    ushort_t* __restrict__ outV,
    int M, int Np, int Kp, int Nreal,
    const float* __restrict__ prelu, int mode)
{
    __shared__ ushort_t Al[3][128 * 32];   // 3 x 8KB
    __shared__ ushort_t Bl[3][128 * 32];   // 3 x 8KB   (48KB total)

    const int nwg = gridDim.x * gridDim.y;
    const int bid = blockIdx.y * gridDim.x + blockIdx.x;
    const int swz = (bid & 7) * (nwg >> 3) + (bid >> 3);
    const int bm = (swz / gridDim.x) * 128;
    const int bn = (swz % gridDim.x) * 128;

    const int tid = threadIdx.x;
    const int wid = tid >> 6, lane = tid & 63;
    const int wr = wid >> 1, wc = wid & 1;
    const int lr = lane & 15, lk = lane >> 4;

    f32x4 acc[4][4];
#pragma unroll
    for (int i = 0; i < 4; ++i)
#pragma unroll
        for (int j = 0; j < 4; ++j)
#pragma unroll
            for (int r = 0; r < 4; ++r) acc[i][j][r] = 0.f;

    const int srow = tid >> 2;
    const int skseg = (tid & 3) * 8;
    const ushort_t* Ag0 = A + (size_t)(bm + srow) * Kp + skseg;
    const ushort_t* Ag1 = A + (size_t)(bm + 64 + srow) * Kp + skseg;
    const ushort_t* Bg0 = Bt + (size_t)(bn + srow) * Kp + skseg;
    const ushort_t* Bg1 = Bt + (size_t)(bn + 64 + srow) * Kp + skseg;

    auto stage = [&](int bi, int k0) {   // 4 vmem instructions per wave
        gload_lds16(Ag0 + k0, &Al[bi][wid * 512]);
        gload_lds16(Ag1 + k0, &Al[bi][2048 + wid * 512]);
        gload_lds16(Bg0 + k0, &Bl[bi][wid * 512]);
        gload_lds16(Bg1 + k0, &Bl[bi][2048 + wid * 512]);
    };

    const int nstep = Kp >> 5;   // 16 or 64 (always >= 3)

    // prologue: fill the 3-deep pipeline
    stage(0, 0);
    stage(1, 32);
    stage(2, 64);
    asm volatile("s_waitcnt vmcnt(8)" ::: "memory");   // buffer 0 landed
    __builtin_amdgcn_s_barrier();
    __builtin_amdgcn_sched_barrier(0);

    int cur = 0;
    for (int t = 0; t < nstep; ++t) {
        bf16x8 af[4], bfr[4];
#pragma unroll
        for (int mi = 0; mi < 4; ++mi)
            af[mi] = *(const bf16x8*)&Al[cur][(wr * 64 + mi * 16 + lr) * 32 + lk * 8];
#pragma unroll
        for (int ni = 0; ni < 4; ++ni)
            bfr[ni] = *(const bf16x8*)&Bl[cur][(wc * 64 + ni * 16 + lr) * 32 + lk * 8];
        __builtin_amdgcn_s_setprio(1);
#pragma unroll
        for (int mi = 0; mi < 4; ++mi)
#pragma unroll
            for (int ni = 0; ni < 4; ++ni)
                acc[mi][ni] = __builtin_amdgcn_mfma_f32_16x16x32_bf16(
                    af[mi], bfr[ni], acc[mi][ni], 0, 0, 0);
        __builtin_amdgcn_s_setprio(0);

        if (t == nstep - 1) break;

        __builtin_amdgcn_sched_barrier(0);
        __builtin_amdgcn_s_barrier();            // all waves done READING cur
        __builtin_amdgcn_sched_barrier(0);

        if (t + 3 < nstep) {
            stage(cur, (t + 3) * 32);            // refill cur with tile t+3
            asm volatile("s_waitcnt vmcnt(8)" ::: "memory");  // t+1's loads done
        } else if (t + 3 == nstep) {
            asm volatile("s_waitcnt vmcnt(4)" ::: "memory");
        } else {
            asm volatile("s_waitcnt vmcnt(0)" ::: "memory");
        }
        __builtin_amdgcn_sched_barrier(0);
        __builtin_amdgcn_s_barrier();            // buffer t+1 ready everywhere
        __builtin_amdgcn_sched_barrier(0);

        cur = cur + 1; if (cur == 3) cur = 0;
    }

    if (mode == 1) {
#pragma unroll
        for (int ni = 0; ni < 4; ++ni) {
            int col = bn + wc * 64 + ni * 16 + lr;
            int reg = col >> 9, c = col & 511;
            bool cok = c < 500;
            int hh, dh;
            if (cok) { hh = c / 125; dh = c - hh * 125; }
            else     { hh = (c - 500) / 3; dh = 125 + (c - 500) % 3; }
            const float* bp = reg == 0 ? bias0 : (reg == 1 ? bias1 : bias2);
            float bv = cok ? bp[c] : 0.f;
#pragma unroll
            for (int mi = 0; mi < 4; ++mi) {
                int row0 = bm + wr * 64 + mi * 16 + lk * 4;
                int b_ = row0 >> 9, n0 = row0 & 511;
                size_t bh = (size_t)b_ * 4 + hh;
                if (reg == 2) {
                    s16x4 pk;
#pragma unroll
                    for (int r = 0; r < 4; ++r) {
                        float val = acc[mi][ni][r] + bv;
                        pk[r] = cok ? (short)f2bf(val) : (short)0;
                    }
                    *(s16x4*)&outV[(bh * 128 + dh) * 512 + n0] = pk;
                } else {
                    ushort_t* dst = reg == 0 ? outB : outK;
#pragma unroll
                    for (int r = 0; r < 4; ++r) {
                        float val = acc[mi][ni][r] + bv;
                        dst[(bh * 512 + n0 + r) * 128 + dh] = cok ? f2bf(val) : 0;
                    }
                }
            }
        }
    } else {
#pragma unroll
        for (int ni = 0; ni < 4; ++ni) {
            int col = bn + wc * 64 + ni * 16 + lr;
            bool cok = col < Nreal;
            float bv = cok ? bias0[col] : 0.f;
            float pv = (prelu && cok) ? prelu[col] : 0.f;
#pragma unroll
            for (int mi = 0; mi < 4; ++mi) {
                int row0 = bm + wr * 64 + mi * 16 + lk * 4;
#pragma unroll
                for (int r = 0; r < 4; ++r) {
                    int row = row0 + r;
                    float val = acc[mi][ni][r] + bv;
                    if (prelu) val = val > 0.f ? val : pv * val;
                    outB[(size_t)row * Np + col] = cok ? f2bf(val) : 0;
                }
            }
        }
    }
}

// ======================= MFMA flash attention v3 (defer-max + exp2 domain) =====
#define KTT 64
__global__ __launch_bounds__(256, 2) void attn_mfma_k(
    const ushort_t* __restrict__ qh, const ushort_t* __restrict__ kh,
    const ushort_t* __restrict__ vT, const unsigned int* __restrict__ abits,
    ushort_t* __restrict__ ctxb)
{
    __shared__ ushort_t Kl[2][KTT * 128];    // 2 x 16KB
    __shared__ ushort_t Vl[2][128 * KTT];    // 2 x 16KB
    __shared__ ushort_t Pl[4][32 * KTT];     // 16KB

    const int bid = blockIdx.x;
    const int wg = (bid & 7) * 64 + (bid >> 3);   // 512 wgs: chunked XCD swizzle
    const int qt2 = wg & 3, bh = wg >> 2;
    const int b = bh >> 2, h = bh & 3;
    const int tid = threadIdx.x, wid = tid >> 6, lane = tid & 63;
    const int lr = lane & 15, lk = lane >> 4;
    const int q0 = qt2 * 128 + wid * 32;          // wave's 32 q rows
    const float scale2 = 0.08944271909999159f * 1.44269504088896f;  // exp2 domain

    bf16x8 qa[2][4];
#pragma unroll
    for (int t = 0; t < 2; ++t) {
        const ushort_t* qbase = qh + ((size_t)bh * 512 + q0 + t * 16 + lr) * 128;
#pragma unroll
        for (int ks = 0; ks < 4; ++ks)
            qa[t][ks] = *(const bf16x8*)&qbase[ks * 32 + lk * 8];
    }

    f32x4 accO[2][8];
#pragma unroll
    for (int t = 0; t < 2; ++t)
#pragma unroll
        for (int i = 0; i < 8; ++i)
#pragma unroll
            for (int r = 0; r < 4; ++r) accO[t][i][r] = 0.f;
    float m_[2][4], l_[2][4];
#pragma unroll
    for (int t = 0; t < 2; ++t)
#pragma unroll
        for (int r = 0; r < 4; ++r) { m_[t][r] = -3e38f; l_[t][r] = 0.f; }

    const unsigned int* ab = abits + ((size_t)b * NNODES + q0) * 16;

    auto stage = [&](int bi, int kt) {
#pragma unroll
        for (int i = 0; i < 4; ++i) {
            int linear = (wid * 4 + i) * 64 + lane;
            int row = linear >> 4, cc = linear & 15;
            int cs = cc ^ (row & 7);
            gload_lds16(kh + ((size_t)bh * 512 + kt * 64 + row) * 128 + cs * 8,
                        &Kl[bi][(wid * 4 + i) * 512]);
        }
#pragma unroll
        for (int i = 0; i < 4; ++i) {
            int linear = (wid * 4 + i) * 64 + lane;
            int row = linear >> 3, cc = linear & 7;
            int cs = cc ^ (row & 7);
            gload_lds16(vT + ((size_t)bh * 128 + row) * 512 + kt * 64 + cs * 8,
                        &Vl[bi][(wid * 4 + i) * 512]);
        }
    };

    stage(0, 0);
    __syncthreads();
    int cur = 0;

    for (int kt = 0; kt < NNODES / KTT; ++kt) {
        if (kt < NNODES / KTT - 1) stage(cur ^ 1, kt + 1);  // prefetch under compute

        unsigned int mw[2][4][2];
#pragma unroll
        for (int t = 0; t < 2; ++t)
#pragma unroll
            for (int r = 0; r < 4; ++r) {
                int qrow = t * 16 + lk * 4 + r;
                mw[t][r][0] = ab[qrow * 16 + kt * 2];
                mw[t][r][1] = ab[qrow * 16 + kt * 2 + 1];
            }

#pragma unroll
        for (int t = 0; t < 2; ++t) {
            f32x4 accS[4];
#pragma unroll
            for (int ni = 0; ni < 4; ++ni)
#pragma unroll
                for (int r = 0; r < 4; ++r) accS[ni][r] = 0.f;
            __builtin_amdgcn_s_setprio(1);
#pragma unroll
            for (int ks = 0; ks < 4; ++ks) {
#pragma unroll
                for (int ni = 0; ni < 4; ++ni) {
                    int row = ni * 16 + lr;
                    int ch = (ks * 4 + lk) ^ (row & 7);
                    bf16x8 kb = *(const bf16x8*)&Kl[cur][row * 128 + ch * 8];
                    accS[ni] = __builtin_amdgcn_mfma_f32_16x16x32_bf16(
                        qa[t][ks], kb, accS[ni], 0, 0, 0);
                }
            }
            __builtin_amdgcn_s_setprio(0);

            float s_all[4][4], mnew[4];
#pragma unroll
            for (int r = 0; r < 4; ++r) {
                float rowmax = -3e38f;
#pragma unroll
                for (int ni = 0; ni < 4; ++ni) {
                    unsigned int word = mw[t][r][ni >> 1];
                    int bit = (ni & 1) * 16 + lr;
                    bool on = (word >> bit) & 1u;
                    float sv = on ? accS[ni][r] * scale2 : -1e9f;
                    s_all[r][ni] = sv;
                    rowmax = fmaxf(rowmax, sv);
                }
                rowmax = fmaxf(rowmax, __shfl_xor(rowmax, 1));
                rowmax = fmaxf(rowmax, __shfl_xor(rowmax, 2));
                rowmax = fmaxf(rowmax, __shfl_xor(rowmax, 4));
                rowmax = fmaxf(rowmax, __shfl_xor(rowmax, 8));
                mnew[r] = fmaxf(m_[t][r], rowmax);
            }
            bool need = false;
#pragma unroll
            for (int r = 0; r < 4; ++r) need = need || (mnew[r] - m_[t][r] > 8.f);
            if (__any(need)) {
#pragma unroll
                for (int r = 0; r < 4; ++r) {
                    float f = exp2f(m_[t][r] - mnew[r]);
                    m_[t][r] = mnew[r];
                    l_[t][r] *= f;
#pragma unroll
                    for (int di = 0; di < 8; ++di) accO[t][di][r] *= f;
                }
            }
#pragma unroll
            for (int r = 0; r < 4; ++r) {
                float p[4], rs = 0.f;
#pragma unroll
                for (int ni = 0; ni < 4; ++ni) {
                    p[ni] = exp2f(s_all[r][ni] - m_[t][r]);
                    rs += p[ni];
                }
                rs += __shfl_xor(rs, 1);
                rs += __shfl_xor(rs, 2);
                rs += __shfl_xor(rs, 4);
                rs += __shfl_xor(rs, 8);
                l_[t][r] += rs;
                int q = t * 16 + lk * 4 + r;
#pragma unroll
                for (int ni = 0; ni < 4; ++ni) {
                    int key = ni * 16 + lr;
                    Pl[wid][q * 64 + (((key >> 3) ^ (q & 7)) << 3) + (key & 7)] = f2bf(p[ni]);
                }
            }
        }

#pragma unroll
        for (int t = 0; t < 2; ++t) {
#pragma unroll
            for (int ksp = 0; ksp < 2; ++ksp) {
                int q = t * 16 + lr;
                int k0p = ksp * 32 + lk * 8;
                bf16x8 pa = *(const bf16x8*)&Pl[wid][q * 64 + (((k0p >> 3) ^ (q & 7)) << 3)];
                __builtin_amdgcn_s_setprio(1);
#pragma unroll
                for (int di = 0; di < 8; ++di) {
                    int row = di * 16 + lr;
                    int ch = (ksp * 4 + lk) ^ (row & 7);
                    bf16x8 vb = *(const bf16x8*)&Vl[cur][row * 64 + ch * 8];
                    accO[t][di] = __builtin_amdgcn_mfma_f32_16x16x32_bf16(
                        pa, vb, accO[t][di], 0, 0, 0);
                }
                __builtin_amdgcn_s_setprio(0);
            }
        }
        __syncthreads();
        cur ^= 1;
    }

    float inv[2][4];
#pragma unroll
    for (int t = 0; t < 2; ++t)
#pragma unroll
        for (int r = 0; r < 4; ++r) inv[t][r] = 1.f / l_[t][r];
#pragma unroll
    for (int t = 0; t < 2; ++t)
#pragma unroll
        for (int di = 0; di < 8; ++di) {
            int d = di * 16 + lr;
            if (d < DHEAD) {
#pragma unroll
                for (int r = 0; r < 4; ++r) {
                    int qg = q0 + t * 16 + lk * 4 + r;
                    ctxb[((size_t)b * NNODES + qg) * KP + h * DHEAD + d] =
                        f2bf(accO[t][di][r] * inv[t][r]);
                }
            }
        }
    if (h == 3) {
        int row = q0 + (lane & 31);
        int c0 = 500 + (lane >> 5) * 6;
#pragma unroll
        for (int j = 0; j < 6; ++j)
            ctxb[((size_t)b * NNODES + row) * KP + c0 + j] = 0;
    }
}

// ======================= layernorm bf16->bf16 (optional residual / final out) ==
__global__ __launch_bounds__(256) void ln_k(
    const ushort_t* __restrict__ x, const ushort_t* __restrict__ res,
    const float* __restrict__ g, const float* __restrict__ bta,
    ushort_t* __restrict__ outB,
    const int* __restrict__ entity_num, float* __restrict__ out, int final_)
{
    size_t row = blockIdx.x;
    const unsigned int* xr = (const unsigned int*)(x + row * KP);
    const unsigned int* rr = res ? (const unsigned int*)(res + row * KP) : nullptr;
    int t = threadIdx.x;           // thread t handles dims 2t, 2t+1
    int d0 = 2 * t;
    unsigned int xv = xr[t];
    float v0 = bf2f((unsigned short)(xv & 0xffff));
    float v1 = bf2f((unsigned short)(xv >> 16));
    if (rr) {
        unsigned int rv = rr[t];
        v0 += bf2f((unsigned short)(rv & 0xffff));
        v1 += bf2f((unsigned short)(rv >> 16));
    }
    if (d0 >= HSZ) v0 = 0.f;
    if (d0 + 1 >= HSZ) v1 = 0.f;
    float s = v0 + v1, s2 = v0 * v0 + v1 * v1;

    __shared__ float red[8];
    int wave = t >> 6, lane = t & 63;
    for (int o = 1; o < 64; o <<= 1) { s += __shfl_xor(s, o); s2 += __shfl_xor(s2, o); }
    if (lane == 0) { red[wave] = s; red[4 + wave] = s2; }
    __syncthreads();
    s  = red[0] + red[1] + red[2] + red[3];
    s2 = red[4] + red[5] + red[6] + red[7];
    float mean = s / HSZ;
    float var  = s2 / HSZ - mean * mean;
    float rstd = rsqrtf(var + 1e-5f);

    float o0 = 0.f, o1 = 0.f;
    if (d0 < HSZ)     o0 = (v0 - mean) * rstd * g[d0] + bta[d0];
    if (d0 + 1 < HSZ) o1 = (v1 - mean) * rstd * g[d0 + 1] + bta[d0 + 1];

    if (!final_) {
        unsigned int pk = (unsigned int)f2bf(o0) | ((unsigned int)f2bf(o1) << 16);
        if (d0 >= HSZ) pk = 0;
        else if (d0 + 1 >= HSZ) pk = (unsigned int)f2bf(o0);
        ((unsigned int*)(outB + row * KP))[t] = pk;
    } else {
        int b = (int)(row >> 9), n = (int)(row & 511);
        int e = entity_num[b];
        int size = e + RRELS;
        bool valid = n < size;
        float* ne = out + (size_t)BB * HSZ + row * HSZ;
        if (d0 < HSZ)     ne[d0]     = valid ? o0 : 0.f;
        if (d0 + 1 < HSZ) ne[d0 + 1] = valid ? o1 : 0.f;
        if (n == e) {
            float* gl = out + (size_t)b * HSZ;
            if (d0 < HSZ)     gl[d0]     = o0;
            if (d0 + 1 < HSZ) gl[d0 + 1] = o1;
        }
        if (t == 0)
            out[(size_t)BB * HSZ + (size_t)BB * NNODES * HSZ + row] =
                (n <= size) ? 1.f : 0.f;
    }
}

// ======================= host =======================
extern "C" void kernel_launch(void* const* d_in, const int* in_sizes, int n_in,
                              void* d_out, int out_size, void* d_ws, size_t ws_size,
                              hipStream_t stream)
{
    const float* ent_vec    = (const float*)d_in[0];
    const int*   entity_num = (const int*)d_in[1];
    const int*   rels       = (const int*)d_in[2];
    const int*   adj        = (const int*)d_in[3];
    const float* rel_embed  = (const float*)d_in[4];
    const float* Wq = (const float*)d_in[5],  *bq = (const float*)d_in[6];
    const float* Wk = (const float*)d_in[7],  *bk = (const float*)d_in[8];
    const float* Wv = (const float*)d_in[9],  *bv = (const float*)d_in[10];
    const float* Wo = (const float*)d_in[11], *bo = (const float*)d_in[12];
    const float* W1 = (const float*)d_in[13], *b1 = (const float*)d_in[14];
    const float* W2 = (const float*)d_in[15], *b2 = (const float*)d_in[16];
    const float* ln1g = (const float*)d_in[17], *ln1b = (const float*)d_in[18];
    const float* ln2g = (const float*)d_in[19], *ln2b = (const float*)d_in[20];
    const float* pa = (const float*)d_in[21];

    const int M = BB * NNODES;               // 16384
    const size_t SP = (size_t)M * KP;        // 8,388,608 bf16

    ushort_t* Xb   = (ushort_t*)d_ws;        // [M][KP]  nodes bf16
    ushort_t* ctxb = Xb + SP;                // attention context
    ushort_t* tb   = ctxb + SP;              // t (ln1 out)
    ushort_t* ob   = tb + SP;                // o (O-proj out)
    ushort_t* fb   = ob + SP;                // f (W2 out)
    ushort_t* h1b  = fb + SP;                // [16384][2048] h1 (67.1MB)
    ushort_t* wqkvb = h1b + (size_t)M * HIDP;     // 2 layers x 786432
    ushort_t* wob  = wqkvb + 2 * 786432;          // 2 layers x 262144
    ushort_t* w1b  = wob + 2 * 262144;            // 2 layers x 1048576
    ushort_t* w2b  = w1b + 2 * (size_t)1048576;   // 2 layers x 1048576

    // attn-phase aliases inside h1b (dead until W1)
    ushort_t* qh  = h1b;                     // [bh][512][128]
    ushort_t* kh  = h1b + SP;
    ushort_t* vTb = h1b + 2 * SP;            // [bh][128][512]

    unsigned int* abits = (unsigned int*)d_out;  // overwritten by final ln_k

    build_nodes_k<<<BB * NNODES, 256, 0, stream>>>(ent_vec, entity_num, rels, rel_embed, Xb);
    adj_bits_k<<<(BB * NNODES * NNODES) / 64 / 4, 256, 0, stream>>>(adj, abits);
    // both layers' weights converted once, up front
    wcvt_t_k<<<1536, 256, 0, stream>>>(Wq, Wk, Wv, Wo, W1, W2, wqkvb, wob, w1b, w2b);

    for (int l = 0; l < NLAYER; ++l) {
        const float* bq_l = bq + (size_t)l * HSZ;
        const float* bk_l = bk + (size_t)l * HSZ;
        const float* bv_l = bv + (size_t)l * HSZ;
        const float* bo_l = bo + (size_t)l * HSZ;
        const float* b1_l = b1 + (size_t)l * HID;
        const float* b2_l = b2 + (size_t)l * HSZ;
        const float* pa_l = pa + (size_t)l * HID;
        ushort_t* wqkv_l = wqkvb + (size_t)l * 786432;
        ushort_t* wo_l   = wob  + (size_t)l * 262144;
        ushort_t* w1_l   = w1b  + (size_t)l * 1048576;
        ushort_t* w2_l   = w2b  + (size_t)l * 1048576;

        // fused QKV: writes qh, kh, and vT (transposed scatter) directly
        dim3 gQKV(1536 / 128, M / 128);  // (12, 128)
        gemm_mfma_k<<<gQKV, 256, 0, stream>>>(Xb, wqkv_l, bq_l, bk_l, bv_l,
                                              qh, kh, vTb,
                                              M, 1536, KP, HSZ, nullptr, 1);

        attn_mfma_k<<<BB * NHEADS_ * 4, 256, 0, stream>>>(qh, kh, vTb, abits, ctxb);

        dim3 gO(KP / 128, M / 128);      // (4, 128)
        gemm_mfma_k<<<gO, 256, 0, stream>>>(ctxb, wo_l, bo_l, nullptr, nullptr,
                                            ob, nullptr, nullptr,
                                            M, KP, KP, HSZ, nullptr, 0);
        ln_k<<<M, 256, 0, stream>>>(ob, nullptr,
                                    ln1g + (size_t)l * HSZ, ln1b + (size_t)l * HSZ,
                                    tb, nullptr, nullptr, 0);

        // FFN un-chunked: one W1 (M x 2048), one W2 (M x 512)
        dim3 g1(HIDP / 128, M / 128);    // (16, 128)
        gemm_mfma_k<<<g1, 256, 0, stream>>>(tb, w1_l, b1_l, nullptr, nullptr,
                                            h1b, nullptr, nullptr,
                                            M, HIDP, KP, HID, pa_l, 0);
        dim3 g2(KP / 128, M / 128);      // (4, 128)
        gemm_mfma_k<<<g2, 256, 0, stream>>>(h1b, w2_l, b2_l, nullptr, nullptr,
                                            fb, nullptr, nullptr,
                                            M, KP, HIDP, HSZ, nullptr, 0);

        int fin = (l == NLAYER - 1) ? 1 : 0;
        ln_k<<<M, 256, 0, stream>>>(fb, tb,
                                    ln2g + (size_t)l * HSZ, ln2b + (size_t)l * HSZ,
                                    Xb, entity_num, (float*)d_out, fin);
    }
}